// Round 5
// baseline (280.123 us; speedup 1.0000x reference)
//
#include <hip/hip_runtime.h>
#include <hip/hip_bf16.h>
#include <stdint.h>

typedef short s16x8 __attribute__((ext_vector_type(8)));   // 8 bf16 bits (4 VGPRs)
typedef float f32x4 __attribute__((ext_vector_type(4)));

#define MFMA16(a, b, c) __builtin_amdgcn_mfma_f32_16x16x32_bf16((a), (b), (c), 0, 0, 0)

// async global->LDS, 16B per lane. LDS dest must be wave-uniform; HW adds lane*16.
__device__ __forceinline__ void gld16(const __bf16* g, __bf16* l) {
  __builtin_amdgcn_global_load_lds(
      (const __attribute__((address_space(1))) unsigned int*)g,
      (__attribute__((address_space(3))) unsigned int*)l, 16, 0, 0);
}

// raw v_exp_f32: skip LLVM's denormal-input range-fixup sequence (~5 VALU/exp).
// Inputs here are attention scores (normal range); output feeds a normalized sum.
__device__ __forceinline__ float fast_exp2(float x) {
#if __has_builtin(__builtin_amdgcn_exp2f)
  return __builtin_amdgcn_exp2f(x);
#else
  float r;
  asm("v_exp_f32 %0, %1" : "=v"(r) : "v"(x));
  return r;
#endif
}

// ---------------- dtype probe (flag=1: bf16 inputs, 0: f32) ----------------
__global__ void probe_kernel(const unsigned short* __restrict__ x, int* __restrict__ flag) {
  int cnt = 0;
  for (int i = threadIdx.x; i < 1024; i += 64) {
    unsigned bits = ((unsigned)x[2 * i]) << 16;
    float f = __uint_as_float(bits);
    float a = fabsf(f);
    if (f == f && a >= 1e-4f && a <= 1e4f) cnt++;
  }
#pragma unroll
  for (int off = 32; off; off >>= 1) cnt += __shfl_down(cnt, off);
  if (threadIdx.x == 0) *flag = (cnt >= 512) ? 1 : 0;
}

// ---------------- convert BOTH raw inputs -> bf16 ws (one launch) ----------------
__global__ void cvt2_kernel(const void* __restrict__ ia, const void* __restrict__ ib,
                            __bf16* __restrict__ oa, __bf16* __restrict__ ob,
                            int nvec, const int* __restrict__ flag) {  // nvec = n/8 per tensor
  const bool isbf = (*flag != 0);
  int i = blockIdx.x * blockDim.x + threadIdx.x;
  int stride = gridDim.x * blockDim.x;
  for (; i < 2 * nvec; i += stride) {
    int v = (i < nvec) ? i : i - nvec;
    const void* in = (i < nvec) ? ia : ib;
    __bf16* out = (i < nvec) ? oa : ob;
    if (isbf) {
      *(uint4*)&out[v * 8] = *(const uint4*)&((const __bf16*)in)[v * 8];
    } else {
      float4 a = *(const float4*)&((const float*)in)[v * 8];
      float4 b = *(const float4*)&((const float*)in)[v * 8 + 4];
      union { __bf16 h[8]; uint4 u; } pk;
      pk.h[0] = (__bf16)a.x; pk.h[1] = (__bf16)a.y; pk.h[2] = (__bf16)a.z; pk.h[3] = (__bf16)a.w;
      pk.h[4] = (__bf16)b.x; pk.h[5] = (__bf16)b.y; pk.h[6] = (__bf16)b.z; pk.h[7] = (__bf16)b.w;
      *(uint4*)&out[v * 8] = pk.u;
    }
  }
}

// ---------------- 4 weight transposes in one launch (z selects; z==3 is Wu 1024x64) ----------------
__global__ void tr3_kernel(const void* __restrict__ w0, const void* __restrict__ w1,
                           const void* __restrict__ w2, const void* __restrict__ w3,
                           __bf16* __restrict__ outbase, __bf16* __restrict__ out3,
                           const int* __restrict__ flag) {
  const bool isbf = (*flag != 0);
  const int z = blockIdx.z;
  if (z == 3 && blockIdx.x >= 2) return;  // Wu has only 64 output cols -> 2 x-tiles
  const void* in = (z == 0) ? w0 : (z == 1) ? w1 : (z == 2) ? w2 : w3;
  __bf16* out = (z == 3) ? out3 : outbase + (size_t)z * 1024 * 1024;
  const int N = (z == 3) ? 64 : 1024;
  __shared__ float tile[32][33];
  int tx = threadIdx.x & 31, ty = threadIdx.x >> 5;
  int n0 = blockIdx.x * 32, k0 = blockIdx.y * 32;
#pragma unroll
  for (int i = 0; i < 32; i += 8) {
    size_t idx = (size_t)(k0 + ty + i) * N + (n0 + tx);
    tile[ty + i][tx] = isbf ? (float)((const __bf16*)in)[idx] : ((const float*)in)[idx];
  }
  __syncthreads();
#pragma unroll
  for (int i = 0; i < 32; i += 8)
    out[(size_t)(n0 + ty + i) * 1024 + (k0 + tx)] = (__bf16)tile[tx][ty + i];
}

// ---------------- m97-style GEMM: C = A[M,K] * Bt[N,K]^T (all-bf16 in) ----------------
template <int BM, int BN, bool BIAS, bool C_WS>
__global__ void __launch_bounds__(256)
gemm_lds(const __bf16* __restrict__ A, const __bf16* __restrict__ Bt,
         void* __restrict__ Cv, const void* __restrict__ biasv,
         int M, int N, int K, float scale, const int* __restrict__ flag) {
  constexpr int BK = 32;
  __shared__ __attribute__((aligned(16))) __bf16 As[BM * BK];
  __shared__ __attribute__((aligned(16))) __bf16 Bs[BN * BK];
  constexpr int WM = BM / 2, WN = BN / 2;
  constexpr int MT = WM / 16, NT = WN / 16;

  const bool raw_bf = (*flag != 0);
  const int tid = threadIdx.x;
  const int wid = tid >> 6, lane = tid & 63;
  const int quad = lane >> 4, l16 = lane & 15;
  const int wm = (wid >> 1) * WM, wn = (wid & 1) * WN;
  const size_t m0 = (size_t)blockIdx.x * BM;
  const size_t n0 = (size_t)blockIdx.y * BN;

  f32x4 acc[MT][NT];
#pragma unroll
  for (int i = 0; i < MT; ++i)
#pragma unroll
    for (int j = 0; j < NT; ++j) acc[i][j] = (f32x4){0.f, 0.f, 0.f, 0.f};

  for (int k0 = 0; k0 < K; k0 += BK) {
#pragma unroll
    for (int i = 0; i < (BM * 4) / 256; ++i) {
      int s = i * 256 + tid, r = s >> 2, c = (s & 3) * 8;
      gld16(&A[(m0 + r) * K + k0 + c], &As[(i * 256 + (tid & 192)) * 8]);
    }
#pragma unroll
    for (int i = 0; i < (BN * 4) / 256; ++i) {
      int s = i * 256 + tid, r = s >> 2, c = (s & 3) * 8;
      gld16(&Bt[(n0 + r) * K + k0 + c], &Bs[(i * 256 + (tid & 192)) * 8]);
    }
    __syncthreads();

    s16x8 af[MT], bf[NT];
#pragma unroll
    for (int mt = 0; mt < MT; ++mt)
      af[mt] = *(const s16x8*)&As[(wm + mt * 16 + l16) * BK + quad * 8];
#pragma unroll
    for (int nt = 0; nt < NT; ++nt)
      bf[nt] = *(const s16x8*)&Bs[(wn + nt * 16 + l16) * BK + quad * 8];
#pragma unroll
    for (int mt = 0; mt < MT; ++mt)
#pragma unroll
      for (int nt = 0; nt < NT; ++nt)
        acc[mt][nt] = MFMA16(af[mt], bf[nt], acc[mt][nt]);
    __syncthreads();
  }

#pragma unroll
  for (int mt = 0; mt < MT; ++mt)
#pragma unroll
    for (int nt = 0; nt < NT; ++nt)
#pragma unroll
      for (int r = 0; r < 4; ++r) {
        size_t row = m0 + wm + mt * 16 + quad * 4 + r;
        size_t col = n0 + wn + nt * 16 + l16;
        float v = acc[mt][nt][r] * scale;
        if (BIAS)
          v += raw_bf ? (float)((const __bf16*)biasv)[col] : ((const float*)biasv)[col];
        if (C_WS || raw_bf) ((__bf16*)Cv)[row * N + col] = (__bf16)v;
        else                ((float*)Cv)[row * N + col] = v;
      }
}

// ---------------- fused q/k/v projection GEMM, XCD-swizzled ----------------
// 1-D grid of 1536. Mapping: xcd = id&7 owns n-tiles {3*xcd..3*xcd+2} (768 KB of
// B resident in that XCD's 4MB L2); j=id>>3 sweeps (m outer, n inner) so 3
// consecutive blocks reuse each A tile from L2.
// n-tile ny: 0..7 -> q (A=yb, scale scq), 8..15 -> k (A=xb, sck),
//            16..23 -> v (A=xb, dst vbT transposed via LDS round-trip).
__global__ void __launch_bounds__(256)
gemm_qkv(const __bf16* __restrict__ xb, const __bf16* __restrict__ yb,
         const __bf16* __restrict__ Wt,
         __bf16* __restrict__ qb, __bf16* __restrict__ kb, __bf16* __restrict__ vbT,
         float scq, float sck) {
  constexpr int BM = 128, BN = 128, BK = 32, K = 1024;
  __shared__ __attribute__((aligned(16))) __bf16 As[BM * BK];
  __shared__ __attribute__((aligned(16))) __bf16 Bs[BN * BK];

  const int tid = threadIdx.x;
  const int wid = tid >> 6, lane = tid & 63;
  const int quad = lane >> 4, l16 = lane & 15;
  const int wm = (wid >> 1) * 64, wn = (wid & 1) * 64;

  const int id = blockIdx.x;
  const int jj = id >> 3;
  const int ny = (id & 7) * 3 + (jj % 3);
  const int mb = jj / 3;
  const size_t m0 = (size_t)mb * BM;
  const size_t n0 = (size_t)ny * BN;
  const __bf16* A = (ny < 8) ? yb : xb;

  f32x4 acc[4][4];
#pragma unroll
  for (int i = 0; i < 4; ++i)
#pragma unroll
    for (int j = 0; j < 4; ++j) acc[i][j] = (f32x4){0.f, 0.f, 0.f, 0.f};

  for (int k0 = 0; k0 < K; k0 += BK) {
#pragma unroll
    for (int i = 0; i < 2; ++i) {
      int s = i * 256 + tid, r = s >> 2, c = (s & 3) * 8;
      gld16(&A[(m0 + r) * K + k0 + c], &As[(i * 256 + (tid & 192)) * 8]);
    }
#pragma unroll
    for (int i = 0; i < 2; ++i) {
      int s = i * 256 + tid, r = s >> 2, c = (s & 3) * 8;
      gld16(&Wt[(n0 + r) * K + k0 + c], &Bs[(i * 256 + (tid & 192)) * 8]);
    }
    __syncthreads();

    s16x8 af[4], bf[4];
#pragma unroll
    for (int mt = 0; mt < 4; ++mt)
      af[mt] = *(const s16x8*)&As[(wm + mt * 16 + l16) * BK + quad * 8];
#pragma unroll
    for (int nt = 0; nt < 4; ++nt)
      bf[nt] = *(const s16x8*)&Bs[(wn + nt * 16 + l16) * BK + quad * 8];
#pragma unroll
    for (int mt = 0; mt < 4; ++mt)
#pragma unroll
      for (int nt = 0; nt < 4; ++nt)
        acc[mt][nt] = MFMA16(af[mt], bf[nt], acc[mt][nt]);
    __syncthreads();
  }

  if (ny < 16) {
    const float s = (ny < 8) ? scq : sck;
    __bf16* C = (ny < 8) ? qb : kb;
    const int nl0 = (ny < 8) ? (int)n0 : (int)n0 - 1024;
#pragma unroll
    for (int mt = 0; mt < 4; ++mt)
#pragma unroll
      for (int nt = 0; nt < 4; ++nt)
#pragma unroll
        for (int r = 0; r < 4; ++r) {
          size_t row = m0 + wm + mt * 16 + quad * 4 + r;
          size_t col = (size_t)(nl0 + wn + nt * 16 + l16);
          C[row * 1024 + col] = (__bf16)(acc[mt][nt][r] * s);
        }
  } else {
    // V region: write transposed vbT[(b*16+h)*64+d][sq] via chunked LDS staging.
    constexpr int LBS = 144;  // buf row stride (elems): 288B = 18*16B, aligned
    __bf16* bufA = As;        // 16*144 = 2304 elems <= 4096
    __bf16* bufB = Bs;
    __bf16* mybuf = (wid & 1) ? bufB : bufA;
    const int colbase = (int)n0 - 2048;
    const int b = (int)(m0 >> 11);
    const int sq0 = (int)(m0 & 2047);
#pragma unroll
    for (int c = 0; c < 4; ++c) {
#pragma unroll
      for (int mt = 0; mt < 4; ++mt) {
        union { __bf16 h[4]; uint2 u; } pk;
#pragma unroll
        for (int r = 0; r < 4; ++r) pk.h[r] = (__bf16)acc[mt][c][r];
        *(uint2*)&mybuf[l16 * LBS + wm + mt * 16 + quad * 4] = pk.u;
      }
      __syncthreads();
      {
        const int p = tid >> 7;
        const __bf16* rb = p ? bufB : bufA;
        const int d16 = (tid >> 3) & 15;
        const int sc = tid & 7;
        const int colg = colbase + p * 64 + c * 16 + d16;
        const int hh = colg >> 6, dd = colg & 63;
        const size_t rowb = ((size_t)b * 16 + hh) * 64 + dd;
        uint4 v0 = *(const uint4*)&rb[d16 * LBS + sc * 16];
        uint4 v1 = *(const uint4*)&rb[d16 * LBS + sc * 16 + 8];
        *(uint4*)&vbT[rowb * 2048 + sq0 + sc * 16] = v0;
        *(uint4*)&vbT[rowb * 2048 + sq0 + sc * 16 + 8] = v1;
      }
      __syncthreads();
    }
  }
}

// ---------------- final projection: out[8192][64] = ob @ WuT^T + bu ----------------
// BM=32, BK=64 -> 256 blocks (1/CU). A staging exactly 256 16B-slots/iter.
__global__ void __launch_bounds__(256)
gemm_out(const __bf16* __restrict__ A, const __bf16* __restrict__ Bt,
         void* __restrict__ Cv, const void* __restrict__ biasv,
         const int* __restrict__ flag) {
  constexpr int BK = 64, K = 1024, N = 64;
  __shared__ __attribute__((aligned(16))) __bf16 As[32 * BK];
  __shared__ __attribute__((aligned(16))) __bf16 Bs[64 * BK];

  const bool raw_bf = (*flag != 0);
  const int tid = threadIdx.x;
  const int wid = tid >> 6, lane = tid & 63;
  const int quad = lane >> 4, l16 = lane & 15;
  const int wm = (wid >> 1) * 16, wn = (wid & 1) * 32;
  const size_t m0 = (size_t)blockIdx.x * 32;

  f32x4 acc[2];
  acc[0] = (f32x4){0.f, 0.f, 0.f, 0.f};
  acc[1] = (f32x4){0.f, 0.f, 0.f, 0.f};

  for (int k0 = 0; k0 < K; k0 += BK) {
    {  // A: 32 rows x 8 chunks = 256 slots
      int r = tid >> 3, c = (tid & 7) * 8;
      gld16(&A[(m0 + r) * K + k0 + c], &As[(tid & 192) * 8]);
    }
#pragma unroll
    for (int i = 0; i < 2; ++i) {  // B: 64 rows x 8 chunks = 512 slots
      int s = i * 256 + tid, r = s >> 3, c = (s & 7) * 8;
      gld16(&Bt[r * K + k0 + c], &Bs[(i * 256 + (tid & 192)) * 8]);
    }
    __syncthreads();

#pragma unroll
    for (int kc = 0; kc < 2; ++kc) {
      s16x8 af = *(const s16x8*)&As[(wm + l16) * BK + kc * 32 + quad * 8];
#pragma unroll
      for (int nt = 0; nt < 2; ++nt) {
        s16x8 bf = *(const s16x8*)&Bs[(wn + nt * 16 + l16) * BK + kc * 32 + quad * 8];
        acc[nt] = MFMA16(af, bf, acc[nt]);
      }
    }
    __syncthreads();
  }

#pragma unroll
  for (int nt = 0; nt < 2; ++nt)
#pragma unroll
    for (int r = 0; r < 4; ++r) {
      size_t row = m0 + wm + quad * 4 + r;
      size_t col = (size_t)(wn + nt * 16 + l16);
      float v = acc[nt][r];
      v += raw_bf ? (float)((const __bf16*)biasv)[col] : ((const float*)biasv)[col];
      if (raw_bf) ((__bf16*)Cv)[row * N + col] = (__bf16)v;
      else        ((float*)Cv)[row * N + col] = v;
    }
}

// ---------------- round-2 dual-dtype GEMM (fallback for small ws) ----------------
template <int BM, int BN, bool BIAS, bool A_WS, bool C_WS>
__global__ void __launch_bounds__(256)
gemm_bt(const void* __restrict__ Av, const __bf16* __restrict__ Bt,
        void* __restrict__ Cv, const void* __restrict__ biasv,
        int M, int N, int K, float scale, const int* __restrict__ flag) {
  constexpr int BK = 32;
  constexpr int LDT = BK + 8;
  __shared__ __attribute__((aligned(16))) __bf16 As[BM][LDT];
  __shared__ __attribute__((aligned(16))) __bf16 Bs[BN][LDT];
  constexpr int WM = BM / 2, WN = BN / 2;
  constexpr int MT = WM / 16, NT = WN / 16;

  const bool raw_bf = (*flag != 0);
  const bool a_bf = A_WS ? true : raw_bf;

  const int tid = threadIdx.x;
  const int wid = tid >> 6, lane = tid & 63;
  const int quad = lane >> 4, l16 = lane & 15;
  const int wm = (wid >> 1) * WM, wn = (wid & 1) * WN;
  const size_t m0 = (size_t)blockIdx.x * BM;
  const size_t n0 = (size_t)blockIdx.y * BN;

  f32x4 acc[MT][NT];
#pragma unroll
  for (int i = 0; i < MT; ++i)
#pragma unroll
    for (int j = 0; j < NT; ++j) acc[i][j] = (f32x4){0.f, 0.f, 0.f, 0.f};

  for (int k0 = 0; k0 < K; k0 += BK) {
    if (a_bf) {
      const __bf16* A = (const __bf16*)Av;
#pragma unroll
      for (int i = 0; i < (BM * 4) / 256; ++i) {
        int s = i * 256 + tid, r = s >> 2, c = (s & 3) * 8;
        *(uint4*)&As[r][c] = *(const uint4*)&A[(m0 + r) * K + k0 + c];
      }
    } else {
      const float* A = (const float*)Av;
#pragma unroll
      for (int i = 0; i < (BM * 8) / 256; ++i) {
        int s = i * 256 + tid, r = s >> 3, c = (s & 7) * 4;
        float4 t = *(const float4*)&A[(m0 + r) * K + k0 + c];
        union { __bf16 h[4]; uint2 u; } cv;
        cv.h[0] = (__bf16)t.x; cv.h[1] = (__bf16)t.y;
        cv.h[2] = (__bf16)t.z; cv.h[3] = (__bf16)t.w;
        *(uint2*)&As[r][c] = cv.u;
      }
    }
#pragma unroll
    for (int i = 0; i < (BN * 4) / 256; ++i) {
      int s = i * 256 + tid, r = s >> 2, c = (s & 3) * 8;
      *(uint4*)&Bs[r][c] = *(const uint4*)&Bt[(n0 + r) * K + k0 + c];
    }
    __syncthreads();

    s16x8 af[MT], bf[NT];
#pragma unroll
    for (int mt = 0; mt < MT; ++mt)
      af[mt] = *(const s16x8*)&As[wm + mt * 16 + l16][quad * 8];
#pragma unroll
    for (int nt = 0; nt < NT; ++nt)
      bf[nt] = *(const s16x8*)&Bs[wn + nt * 16 + l16][quad * 8];
#pragma unroll
    for (int mt = 0; mt < MT; ++mt)
#pragma unroll
      for (int nt = 0; nt < NT; ++nt)
        acc[mt][nt] = MFMA16(af[mt], bf[nt], acc[mt][nt]);
    __syncthreads();
  }

#pragma unroll
  for (int mt = 0; mt < MT; ++mt)
#pragma unroll
    for (int nt = 0; nt < NT; ++nt)
#pragma unroll
      for (int r = 0; r < 4; ++r) {
        size_t row = m0 + wm + mt * 16 + quad * 4 + r;
        size_t col = n0 + wn + nt * 16 + l16;
        float v = acc[mt][nt][r] * scale;
        if (BIAS)
          v += raw_bf ? (float)((const __bf16*)biasv)[col] : ((const float*)biasv)[col];
        if (C_WS || raw_bf) ((__bf16*)Cv)[row * N + col] = (__bf16)v;
        else                ((float*)Cv)[row * N + col] = v;
      }
}

// ---------------- flash attention v10: V double-buffer, 3-deep DMA pipeline ----------------
// 1-D grid 1024, 256 thr (4 waves, wave w owns q-rows [w*32,w*32+32)).
// Swizzle: xcd = id&7 serves bh in {xcd*8..xcd*8+7} -> KV tiles L2-resident.
// R5 change vs v9: Vt[2] double buffer. LDS 32768 -> 40960 B; 40960 x 4 = 163840 B
// = exactly 160 KiB -> still 4 blocks/CU (grid 1024 = 4/CU exact). New schedule:
//   top of tile t:  vmcnt(0)+barrier (waits K(t) issued mid t-1, V(t) issued top t-1
//                   -- both covered by >= half a tile of compute)
//                   issue V(t+1) -> Vt[c^1]   (full tile to land)
//   QK^T(t) from Ks
//   mid barrier: NO vmcnt (was the exposed V(t) drain: V had only QK^T to cover)
//   issue K(t+1) -> Ks; PV(t) from Vt[c]
// Mid barrier safety: QK^T ds_reads are data-consumed before the barrier (compiler
// lgkmcnt); K-staging after it writes a buffer all waves finished reading; V(t+1)
// DMA targets the other V buffer. Compiler memory fences around raw s_barrier.
__global__ void __launch_bounds__(256, 4)
attn5_kernel(const __bf16* __restrict__ qg, const __bf16* __restrict__ kg,
             const __bf16* __restrict__ vtg, __bf16* __restrict__ og) {
  constexpr int SKV = 2048, QT = 128, KT = 64, SS = 1024, VS = 2048;
  __shared__ __attribute__((aligned(16))) __bf16 QP[QT * 64];    // Q [128][64] then P [128][64] swz
  __shared__ __attribute__((aligned(16))) __bf16 Ks[KT * 64];    // [key][d], XOR-src-swizzled
  __shared__ __attribute__((aligned(16))) __bf16 Vt[2][64 * KT]; // [d][key] x2, XOR-src-swizzled

  const int tid = threadIdx.x;
  const int wid = tid >> 6, lane = tid & 63;
  const int quad = lane >> 4, l16 = lane & 15;

  const int id = blockIdx.x;
  const int j = id >> 3;
  const int bh = (id & 7) * 8 + (j & 7);
  const int b = bh >> 4, h = bh & 15;
  const int q0 = (j >> 3) * QT;

  const __bf16* qb = qg + (size_t)b * 2048 * SS + h * 64;
  const __bf16* kb = kg + (size_t)b * 2048 * SS + h * 64;
  const __bf16* vtb = vtg + (size_t)bh * 64 * VS;
  __bf16* ob = og + (size_t)b * 2048 * SS + h * 64;

#pragma unroll
  for (int i = 0; i < 4; ++i) {
    int s = i * 256 + tid, r = s >> 3, slot = s & 7, c = slot ^ (r & 7);
    gld16(&qb[(size_t)(q0 + r) * SS + c * 8], &QP[(i * 256 + (tid & 192)) * 8]);
  }
  __syncthreads();

  s16x8 qf[2][2];
#pragma unroll
  for (int nt = 0; nt < 2; ++nt)
#pragma unroll
    for (int kc = 0; kc < 2; ++kc) {
      int row = wid * 32 + nt * 16 + l16;
      qf[nt][kc] = *(const s16x8*)&QP[row * 64 + (((quad + kc * 4) ^ (row & 7)) * 8)];
    }
  __syncthreads();  // QP now reusable as P; also drains Q DMA fully

  // ---- hoist all loop-invariant LDS element offsets into registers ----
  // P layout: [row][64] with 8-elem-unit XOR swizzle: unit' = unit ^ (row&7).
  int koff[4][2];   // Ks read (kfa): [mtk][kc]
  int pwoff[2][4];  // P write: [ntq][mtk]  (b64 at unit'*8 + (quad&1)*4)
  int proff[2][2];  // P read (pf): [mt2][kc] (b128 at unit'*8)
  int voff[2][4];   // Vt read (vf): [kc][ntd] (within one V buffer)
#pragma unroll
  for (int mtk = 0; mtk < 4; ++mtk)
#pragma unroll
    for (int kc = 0; kc < 2; ++kc) {
      int row = mtk * 16 + l16;
      koff[mtk][kc] = row * 64 + (((quad + kc * 4) ^ (row & 7)) * 8);
    }
#pragma unroll
  for (int ntq = 0; ntq < 2; ++ntq) {
    int row = wid * 32 + ntq * 16 + l16;
#pragma unroll
    for (int mtk = 0; mtk < 4; ++mtk)
      pwoff[ntq][mtk] = row * 64 + (((2 * mtk + (quad >> 1)) ^ (row & 7)) * 8) + (quad & 1) * 4;
#pragma unroll
    for (int kc = 0; kc < 2; ++kc)
      proff[ntq][kc] = row * 64 + (((4 * kc + quad) ^ (row & 7)) * 8);
  }
#pragma unroll
  for (int kc = 0; kc < 2; ++kc)
#pragma unroll
    for (int ntd = 0; ntd < 4; ++ntd) {
      int d = ntd * 16 + l16;
      voff[kc][ntd] = d * 64 + (((kc * 4 + quad) ^ (d & 7)) * 8);
    }

  float lsum[2] = {0.f, 0.f};
  f32x4 oacc[2][4];
#pragma unroll
  for (int mt = 0; mt < 2; ++mt)
#pragma unroll
    for (int nt = 0; nt < 4; ++nt) oacc[mt][nt] = (f32x4){0.f, 0.f, 0.f, 0.f};

  // prologue: stage V(0) -> Vt[0] and K(0) -> Ks
#pragma unroll
  for (int i = 0; i < 2; ++i) {
    int s = i * 256 + tid, r = s >> 3, slot = s & 7, c = slot ^ (r & 7);
    gld16(&vtb[(size_t)r * VS + c * 8], &Vt[0][(i * 256 + (tid & 192)) * 8]);
  }
#pragma unroll
  for (int i = 0; i < 2; ++i) {
    int s = i * 256 + tid, r = s >> 3, slot = s & 7, c = slot ^ (r & 7);
    gld16(&kb[(size_t)r * SS + c * 8], &Ks[(i * 256 + (tid & 192)) * 8]);
  }

  for (int kv = 0; kv < SKV; kv += KT) {
    const int cur = (kv >> 6) & 1;
    // K(kv) and V(kv) landed (issued >= half a tile ago); all waves done with
    // Ks(kv-KT) and Vt[cur^1](kv-KT).
    asm volatile("s_waitcnt vmcnt(0)" ::: "memory");
    __builtin_amdgcn_s_barrier();
    asm volatile("" ::: "memory");

    // stage V(kv+KT) -> Vt[cur^1]; has a full tile (QK^T + PV) to land
    if (kv + KT < SKV) {
#pragma unroll
      for (int i = 0; i < 2; ++i) {
        int s = i * 256 + tid, r = s >> 3, slot = s & 7, c = slot ^ (r & 7);
        gld16(&vtb[(size_t)r * VS + (kv + KT) + c * 8],
              &Vt[cur ^ 1][(i * 256 + (tid & 192)) * 8]);
      }
    }

    // S^T[key][q] = K·Q^T ; exp2 ; packed b64 P store (wave-private rows)
#pragma unroll
    for (int mtk = 0; mtk < 4; ++mtk) {
      s16x8 kfa[2];
#pragma unroll
      for (int kc = 0; kc < 2; ++kc)
        kfa[kc] = *(const s16x8*)&Ks[koff[mtk][kc]];
#pragma unroll
      for (int ntq = 0; ntq < 2; ++ntq) {
        f32x4 z = (f32x4){0.f, 0.f, 0.f, 0.f};
        __builtin_amdgcn_s_setprio(1);
        z = MFMA16(kfa[0], qf[ntq][0], z);
        z = MFMA16(kfa[1], qf[ntq][1], z);
        __builtin_amdgcn_s_setprio(0);
        union { __bf16 hh[4]; uint2 u; } pk;
        float p0 = fast_exp2(z[0]);
        float p1 = fast_exp2(z[1]);
        float p2 = fast_exp2(z[2]);
        float p3 = fast_exp2(z[3]);
        pk.hh[0] = (__bf16)p0; pk.hh[1] = (__bf16)p1;
        pk.hh[2] = (__bf16)p2; pk.hh[3] = (__bf16)p3;
        lsum[ntq] += (p0 + p1) + (p2 + p3);
        *(uint2*)&QP[pwoff[ntq][mtk]] = pk.u;
      }
    }

    // mid barrier: all waves done reading Ks(kv). NO vmcnt drain here (V(kv)
    // already resident; V(kv+KT) targets the other buffer).
    asm volatile("" ::: "memory");
    __builtin_amdgcn_s_barrier();
    asm volatile("" ::: "memory");

    // stage K(kv+KT) -> Ks; overlaps PV below (which reads only Vt[cur] + QP)
    if (kv + KT < SKV) {
#pragma unroll
      for (int i = 0; i < 2; ++i) {
        int s = i * 256 + tid, r = s >> 3, slot = s & 7, c = slot ^ (r & 7);
        gld16(&kb[(size_t)(kv + KT + r) * SS + c * 8], &Ks[(i * 256 + (tid & 192)) * 8]);
      }
    }

    // O += P·V  (P rows wave-private; per-wave LDS ops in-order)
#pragma unroll
    for (int kc = 0; kc < 2; ++kc) {
      s16x8 pf[2], vf[4];
#pragma unroll
      for (int mt2 = 0; mt2 < 2; ++mt2)
        pf[mt2] = *(const s16x8*)&QP[proff[mt2][kc]];
#pragma unroll
      for (int ntd = 0; ntd < 4; ++ntd)
        vf[ntd] = *(const s16x8*)&Vt[cur][voff[kc][ntd]];
      __builtin_amdgcn_s_setprio(1);
#pragma unroll
      for (int mt2 = 0; mt2 < 2; ++mt2)
#pragma unroll
        for (int ntd = 0; ntd < 4; ++ntd)
          oacc[mt2][ntd] = MFMA16(pf[mt2], vf[ntd], oacc[mt2][ntd]);
      __builtin_amdgcn_s_setprio(0);
    }
  }

#pragma unroll
  for (int nt = 0; nt < 2; ++nt) {
    lsum[nt] += __shfl_xor(lsum[nt], 16);
    lsum[nt] += __shfl_xor(lsum[nt], 32);
  }
#pragma unroll
  for (int mt2 = 0; mt2 < 2; ++mt2)
#pragma unroll
    for (int r = 0; r < 4; ++r) {
      float l = __shfl(lsum[mt2], quad * 4 + r);
      float linv = 1.0f / l;
      int row = q0 + wid * 32 + mt2 * 16 + quad * 4 + r;
#pragma unroll
      for (int ntd = 0; ntd < 4; ++ntd)
        ob[(size_t)row * SS + ntd * 16 + l16] = (__bf16)(oacc[mt2][ntd][r] * linv);
    }
}

// ---------------- round-3 flash attention (fallback path, scalar V scatter) ----------------
__global__ void __launch_bounds__(256)
attn_kernel(const __bf16* __restrict__ qg, const __bf16* __restrict__ kg,
            const __bf16* __restrict__ vg, __bf16* __restrict__ og) {
  constexpr int D = 64, SKV = 2048, QT = 128, KT = 64, SS = 1024;
  constexpr int LDP = 72, LDV = 72;
  __shared__ __attribute__((aligned(16))) __bf16 QP[QT * LDP];
  __shared__ __attribute__((aligned(16))) __bf16 Ks[KT * D];
  __shared__ __attribute__((aligned(16))) __bf16 Vts[D * LDV];

  const int tid = threadIdx.x;
  const int wid = tid >> 6, lane = tid & 63;
  const int quad = lane >> 4, l16 = lane & 15;
  const int b = blockIdx.y >> 4, h = blockIdx.y & 15;
  const int q0 = blockIdx.x * QT;

  const __bf16* qb = qg + (size_t)b * 2048 * SS + h * D;
  const __bf16* kb = kg + (size_t)b * 2048 * SS + h * D;
  const __bf16* vb = vg + (size_t)b * 2048 * SS + h * D;
  __bf16* ob = og + (size_t)b * 2048 * SS + h * D;

#pragma unroll
  for (int i = 0; i < 4; ++i) {
    int s = i * 256 + tid, r = s >> 3, slot = s & 7, c = slot ^ (r & 7);
    gld16(&qb[(size_t)(q0 + r) * SS + c * 8], &QP[(i * 256 + (tid & 192)) * 8]);
  }
  __syncthreads();

  s16x8 qf[2][2];
#pragma unroll
  for (int nt = 0; nt < 2; ++nt)
#pragma unroll
    for (int kc = 0; kc < 2; ++kc) {
      int row = wid * 32 + nt * 16 + l16;
      qf[nt][kc] = *(const s16x8*)&QP[row * 64 + (((quad + kc * 4) ^ (row & 7)) * 8)];
    }
  __syncthreads();

  float lsum[2] = {0.f, 0.f};
  f32x4 oacc[2][4];
#pragma unroll
  for (int mt = 0; mt < 2; ++mt)
#pragma unroll
    for (int nt = 0; nt < 4; ++nt) oacc[mt][nt] = (f32x4){0.f, 0.f, 0.f, 0.f};

  for (int kv = 0; kv < SKV; kv += KT) {
#pragma unroll
    for (int i = 0; i < 2; ++i) {
      int s = i * 256 + tid, r = s >> 3, slot = s & 7, c = slot ^ (r & 7);
      gld16(&kb[(size_t)(kv + r) * SS + c * 8], &Ks[(i * 256 + (tid & 192)) * 8]);
    }
#pragma unroll
    for (int i = 0; i < 2; ++i) {
      int s = i * 256 + tid, r = s >> 3, mc = s & 7;
      uint4 t = *(const uint4*)&vb[(size_t)(kv + r) * SS + mc * 8];
      const __bf16* tp = (const __bf16*)&t;
      int colbase = r ^ (mc << 3);
#pragma unroll
      for (int jj = 0; jj < 8; ++jj) Vts[(mc * 8 + jj) * LDV + colbase] = tp[jj];
    }
    __syncthreads();

#pragma unroll
    for (int mtk = 0; mtk < 4; ++mtk) {
      s16x8 kfa[2];
#pragma unroll
      for (int kc = 0; kc < 2; ++kc) {
        int row = mtk * 16 + l16;
        kfa[kc] = *(const s16x8*)&Ks[row * 64 + (((quad + kc * 4) ^ (row & 7)) * 8)];
      }
#pragma unroll
      for (int ntq = 0; ntq < 2; ++ntq) {
        f32x4 z = (f32x4){0.f, 0.f, 0.f, 0.f};
        z = MFMA16(kfa[0], qf[ntq][0], z);
        z = MFMA16(kfa[1], qf[ntq][1], z);
        union { __bf16 hh[4]; uint2 u; } pk;
        float ps = 0.f;
#pragma unroll
        for (int r = 0; r < 4; ++r) {
          float p = __builtin_exp2f(fminf(z[r], 80.f));
          ps += p;
          pk.hh[r] = (__bf16)p;
        }
        lsum[ntq] += ps;
        int row = wid * 32 + ntq * 16 + l16;
        *(uint2*)&QP[row * LDP + mtk * 16 + quad * 4] = pk.u;
      }
    }

#pragma unroll
    for (int kc = 0; kc < 2; ++kc) {
      s16x8 pf[2], vf[4];
#pragma unroll
      for (int mt2 = 0; mt2 < 2; ++mt2)
        pf[mt2] = *(const s16x8*)&QP[(wid * 32 + mt2 * 16 + l16) * LDP + kc * 32 + quad * 8];
#pragma unroll
      for (int ntd = 0; ntd < 4; ++ntd) {
        int d = ntd * 16 + l16;
        int col0 = (kc * 32 + quad * 8) ^ ((((d >> 3) & 7)) << 3);
        vf[ntd] = *(const s16x8*)&Vts[d * LDV + col0];
      }
#pragma unroll
      for (int mt2 = 0; mt2 < 2; ++mt2)
#pragma unroll
        for (int ntd = 0; ntd < 4; ++ntd)
          oacc[mt2][ntd] = MFMA16(pf[mt2], vf[ntd], oacc[mt2][ntd]);
    }
    __syncthreads();
  }

#pragma unroll
  for (int nt = 0; nt < 2; ++nt) {
    lsum[nt] += __shfl_xor(lsum[nt], 16);
    lsum[nt] += __shfl_xor(lsum[nt], 32);
  }
#pragma unroll
  for (int mt2 = 0; mt2 < 2; ++mt2)
#pragma unroll
    for (int r = 0; r < 4; ++r) {
      float l = __shfl(lsum[mt2], quad * 4 + r);
      float linv = 1.0f / l;
      int row = q0 + wid * 32 + mt2 * 16 + quad * 4 + r;
#pragma unroll
      for (int ntd = 0; ntd < 4; ++ntd)
        ob[(size_t)row * SS + ntd * 16 + l16] = (__bf16)(oacc[mt2][ntd][r] * linv);
    }
}

// ---------------- launch ----------------
extern "C" void kernel_launch(void* const* d_in, const int* in_sizes, int n_in,
                              void* d_out, int out_size, void* d_ws, size_t ws_size,
                              hipStream_t stream) {
  const void* x  = d_in[0];  // [4,2048,1024]
  const void* y  = d_in[1];
  const void* Wv = d_in[2];  // [1024,1024] (in,out)
  const void* Wk = d_in[3];
  const void* Wq = d_in[4];
  const void* Wu = d_in[5];  // [1024,64]
  const void* bu = d_in[6];  // [64]

  const float sc  = 0.17677669529663687f;                        // 1024^-0.25
  const float scq = 0.17677669529663687f * 1.4426950408889634f;  // + log2(e) fold

  constexpr size_t NTOK = (size_t)8192 * 1024;
  constexpr size_t TB = NTOK * 2;

  char* p = (char*)d_ws;
  int* flag = (int*)p; p += 256;
  __bf16* qb = (__bf16*)p; p += TB;
  __bf16* kb = (__bf16*)p; p += TB;
  __bf16* vb = (__bf16*)p; p += TB;   // fast path: used as vbT
  __bf16* WuT = (__bf16*)p; p += (size_t)64 * 1024 * 2;

  probe_kernel<<<1, 64, 0, stream>>>((const unsigned short*)x, flag);

  const size_t fast_need = 256 + 3 * TB + (size_t)64 * 1024 * 2 + 2 * TB + 3 * (size_t)1024 * 1024 * 2;
  if (ws_size >= fast_need) {
    __bf16* xb = (__bf16*)p; p += TB;
    __bf16* yb = (__bf16*)p; p += TB;
    __bf16* WqkvT = (__bf16*)p;  // 3 x [1024][1024]
    __bf16* vbT = vb;
    __bf16* ob  = xb;  // xb dead after gemm_qkv

    cvt2_kernel<<<2048, 256, 0, stream>>>(x, y, xb, yb, (int)(NTOK / 8), flag);
    tr3_kernel<<<dim3(32, 32, 4), 256, 0, stream>>>(Wq, Wk, Wv, Wu, WqkvT, WuT, flag);

    gemm_qkv<<<dim3(1536), 256, 0, stream>>>(xb, yb, WqkvT, qb, kb, vbT, scq, sc);

    attn5_kernel<<<dim3(1024), 256, 0, stream>>>(qb, kb, vbT, ob);

    gemm_out<<<dim3(256), 256, 0, stream>>>(ob, WuT, d_out, bu, flag);
  } else {
    __bf16* region = (__bf16*)p;
    __bf16* WqT = region;
    __bf16* WkT = region + (size_t)1024 * 1024;
    __bf16* WvT = region + (size_t)2 * 1024 * 1024;
    __bf16* ob  = region;

    tr3_kernel<<<dim3(32, 32, 4), 256, 0, stream>>>(Wq, Wk, Wv, Wu, WqT, WuT, flag);

    gemm_bt<128, 128, false, false, true><<<dim3(64, 8), 256, 0, stream>>>(
        y, WqT, qb, nullptr, 8192, 1024, 1024, scq, flag);
    gemm_bt<128, 128, false, false, true><<<dim3(64, 8), 256, 0, stream>>>(
        x, WkT, kb, nullptr, 8192, 1024, 1024, sc, flag);
    gemm_bt<128, 128, false, false, true><<<dim3(64, 8), 256, 0, stream>>>(
        x, WvT, vb, nullptr, 8192, 1024, 1024, 1.0f, flag);

    attn_kernel<<<dim3(16, 64), 256, 0, stream>>>(qb, kb, vb, ob);

    gemm_bt<128, 64, true, true, false><<<dim3(64, 1), 256, 0, stream>>>(
        ob, WuT, d_out, bu, 8192, 64, 1024, 1.0f, flag);
  }
}

// Round 6
// 276.484 us; speedup vs baseline: 1.0132x; 1.0132x over previous
//
#include <hip/hip_runtime.h>
#include <hip/hip_bf16.h>
#include <stdint.h>

typedef short s16x8 __attribute__((ext_vector_type(8)));   // 8 bf16 bits (4 VGPRs)
typedef float f32x4 __attribute__((ext_vector_type(4)));

#define MFMA16(a, b, c) __builtin_amdgcn_mfma_f32_16x16x32_bf16((a), (b), (c), 0, 0, 0)

// async global->LDS, 16B per lane. LDS dest must be wave-uniform; HW adds lane*16.
__device__ __forceinline__ void gld16(const __bf16* g, __bf16* l) {
  __builtin_amdgcn_global_load_lds(
      (const __attribute__((address_space(1))) unsigned int*)g,
      (__attribute__((address_space(3))) unsigned int*)l, 16, 0, 0);
}

// raw v_exp_f32: skip LLVM's denormal-input range-fixup sequence (~5 VALU/exp).
__device__ __forceinline__ float fast_exp2(float x) {
#if __has_builtin(__builtin_amdgcn_exp2f)
  return __builtin_amdgcn_exp2f(x);
#else
  float r;
  asm("v_exp_f32 %0, %1" : "=v"(r) : "v"(x));
  return r;
#endif
}

// probe logic: sample 1024 interleaved shorts of x; if they decode to sane bf16,
// input is bf16, else f32. Deterministic -> every block computes the same answer.
__device__ __forceinline__ int probe_cnt_wave(const unsigned short* xs, int lane) {
  int cnt = 0;
  for (int i = lane; i < 1024; i += 64) {
    unsigned bits = ((unsigned)xs[2 * i]) << 16;
    float f = __uint_as_float(bits);
    float a = fabsf(f);
    if (f == f && a >= 1e-4f && a <= 1e4f) cnt++;
  }
#pragma unroll
  for (int off = 32; off; off >>= 1) cnt += __shfl_down(cnt, off);
  return cnt;  // valid in lane 0
}

// ---------------- dtype probe kernel (fallback path only) ----------------
__global__ void probe_kernel(const unsigned short* __restrict__ x, int* __restrict__ flag) {
  int cnt = probe_cnt_wave(x, threadIdx.x & 63);
  if (threadIdx.x == 0) *flag = (cnt >= 512) ? 1 : 0;
}

// ---------------- fused pre-kernel: inline probe + cvt(x,y)->bf16 + 4 weight transposes ----
// grid 5184 x 256: blocks [0,2048) convert x,y; blocks [2048,5184) transpose
// Wq/Wk/Wv (z=0..2, 1024 blocks each) and Wu (z=3, 64 blocks).
__global__ void __launch_bounds__(256)
pre_kernel(const void* __restrict__ x, const void* __restrict__ y,
           const void* __restrict__ w0, const void* __restrict__ w1,
           const void* __restrict__ w2, const void* __restrict__ w3,
           __bf16* __restrict__ xb, __bf16* __restrict__ yb,
           __bf16* __restrict__ wqkvT, __bf16* __restrict__ wuT) {
  __shared__ int sflag;
  __shared__ float tile[32][33];
  if (threadIdx.x < 64) {
    int cnt = probe_cnt_wave((const unsigned short*)x, threadIdx.x);
    if (threadIdx.x == 0) sflag = (cnt >= 512) ? 1 : 0;
  }
  __syncthreads();
  const bool isbf = (sflag != 0);

  const int bid = blockIdx.x;
  if (bid < 2048) {
    constexpr int NV = (int)((size_t)8192 * 1024 / 8);  // vectors of 8 per tensor
    int i = bid * 256 + threadIdx.x;
    const int stride = 2048 * 256;
    for (; i < 2 * NV; i += stride) {
      int v = (i < NV) ? i : i - NV;
      const void* in = (i < NV) ? x : y;
      __bf16* out = (i < NV) ? xb : yb;
      if (isbf) {
        *(uint4*)&out[v * 8] = *(const uint4*)&((const __bf16*)in)[v * 8];
      } else {
        float4 a = *(const float4*)&((const float*)in)[v * 8];
        float4 b = *(const float4*)&((const float*)in)[v * 8 + 4];
        union { __bf16 h[8]; uint4 u; } pk;
        pk.h[0] = (__bf16)a.x; pk.h[1] = (__bf16)a.y; pk.h[2] = (__bf16)a.z; pk.h[3] = (__bf16)a.w;
        pk.h[4] = (__bf16)b.x; pk.h[5] = (__bf16)b.y; pk.h[6] = (__bf16)b.z; pk.h[7] = (__bf16)b.w;
        *(uint4*)&out[v * 8] = pk.u;
      }
    }
  } else {
    int t = bid - 2048;
    int z, bx, by;
    if (t < 3072) { z = t >> 10; int xy = t & 1023; bx = xy & 31; by = xy >> 5; }
    else          { z = 3; int u = t - 3072; bx = u & 1; by = u >> 1; }
    const void* in = (z == 0) ? w0 : (z == 1) ? w1 : (z == 2) ? w2 : w3;
    __bf16* out = (z == 3) ? wuT : wqkvT + (size_t)z * 1024 * 1024;
    const int N = (z == 3) ? 64 : 1024;
    int tx = threadIdx.x & 31, ty = threadIdx.x >> 5;
    int n0 = bx * 32, k0 = by * 32;
#pragma unroll
    for (int i = 0; i < 32; i += 8) {
      size_t idx = (size_t)(k0 + ty + i) * N + (n0 + tx);
      tile[ty + i][tx] = isbf ? (float)((const __bf16*)in)[idx] : ((const float*)in)[idx];
    }
    __syncthreads();
#pragma unroll
    for (int i = 0; i < 32; i += 8)
      out[(size_t)(n0 + ty + i) * 1024 + (k0 + tx)] = (__bf16)tile[tx][ty + i];
  }
}

// ---------------- 4 weight transposes (flag version, fallback path) ----------------
__global__ void tr3_kernel(const void* __restrict__ w0, const void* __restrict__ w1,
                           const void* __restrict__ w2, const void* __restrict__ w3,
                           __bf16* __restrict__ outbase, __bf16* __restrict__ out3,
                           const int* __restrict__ flag) {
  const bool isbf = (*flag != 0);
  const int z = blockIdx.z;
  if (z == 3 && blockIdx.x >= 2) return;
  const void* in = (z == 0) ? w0 : (z == 1) ? w1 : (z == 2) ? w2 : w3;
  __bf16* out = (z == 3) ? out3 : outbase + (size_t)z * 1024 * 1024;
  const int N = (z == 3) ? 64 : 1024;
  __shared__ float tile[32][33];
  int tx = threadIdx.x & 31, ty = threadIdx.x >> 5;
  int n0 = blockIdx.x * 32, k0 = blockIdx.y * 32;
#pragma unroll
  for (int i = 0; i < 32; i += 8) {
    size_t idx = (size_t)(k0 + ty + i) * N + (n0 + tx);
    tile[ty + i][tx] = isbf ? (float)((const __bf16*)in)[idx] : ((const float*)in)[idx];
  }
  __syncthreads();
#pragma unroll
  for (int i = 0; i < 32; i += 8)
    out[(size_t)(n0 + ty + i) * 1024 + (k0 + tx)] = (__bf16)tile[tx][ty + i];
}

// ---------------- fused q/k/v projection GEMM, XCD-swizzled ----------------
// 1-D grid of 1536. xcd = id&7 owns n-tiles {3*xcd..3*xcd+2}; j=id>>3 sweeps
// (m outer, n inner) so 3 consecutive blocks reuse each A tile from L2.
// n-tile ny: 0..7 -> q (A=yb, scale scq), 8..15 -> k (A=xb, sck),
//            16..23 -> v (A=xb, dst vbT transposed via LDS round-trip).
__global__ void __launch_bounds__(256)
gemm_qkv(const __bf16* __restrict__ xb, const __bf16* __restrict__ yb,
         const __bf16* __restrict__ Wt,
         __bf16* __restrict__ qb, __bf16* __restrict__ kb, __bf16* __restrict__ vbT,
         float scq, float sck) {
  constexpr int BM = 128, BN = 128, BK = 32, K = 1024;
  __shared__ __attribute__((aligned(16))) __bf16 As[BM * BK];
  __shared__ __attribute__((aligned(16))) __bf16 Bs[BN * BK];

  const int tid = threadIdx.x;
  const int wid = tid >> 6, lane = tid & 63;
  const int quad = lane >> 4, l16 = lane & 15;
  const int wm = (wid >> 1) * 64, wn = (wid & 1) * 64;

  const int id = blockIdx.x;
  const int jj = id >> 3;
  const int ny = (id & 7) * 3 + (jj % 3);
  const int mb = jj / 3;
  const size_t m0 = (size_t)mb * BM;
  const size_t n0 = (size_t)ny * BN;
  const __bf16* A = (ny < 8) ? yb : xb;

  f32x4 acc[4][4];
#pragma unroll
  for (int i = 0; i < 4; ++i)
#pragma unroll
    for (int j = 0; j < 4; ++j) acc[i][j] = (f32x4){0.f, 0.f, 0.f, 0.f};

  for (int k0 = 0; k0 < K; k0 += BK) {
#pragma unroll
    for (int i = 0; i < 2; ++i) {
      int s = i * 256 + tid, r = s >> 2, c = (s & 3) * 8;
      gld16(&A[(m0 + r) * K + k0 + c], &As[(i * 256 + (tid & 192)) * 8]);
    }
#pragma unroll
    for (int i = 0; i < 2; ++i) {
      int s = i * 256 + tid, r = s >> 2, c = (s & 3) * 8;
      gld16(&Wt[(n0 + r) * K + k0 + c], &Bs[(i * 256 + (tid & 192)) * 8]);
    }
    __syncthreads();

    s16x8 af[4], bf[4];
#pragma unroll
    for (int mt = 0; mt < 4; ++mt)
      af[mt] = *(const s16x8*)&As[(wm + mt * 16 + l16) * BK + quad * 8];
#pragma unroll
    for (int nt = 0; nt < 4; ++nt)
      bf[nt] = *(const s16x8*)&Bs[(wn + nt * 16 + l16) * BK + quad * 8];
#pragma unroll
    for (int mt = 0; mt < 4; ++mt)
#pragma unroll
      for (int nt = 0; nt < 4; ++nt)
        acc[mt][nt] = MFMA16(af[mt], bf[nt], acc[mt][nt]);
    __syncthreads();
  }

  if (ny < 16) {
    const float s = (ny < 8) ? scq : sck;
    __bf16* C = (ny < 8) ? qb : kb;
    const int nl0 = (ny < 8) ? (int)n0 : (int)n0 - 1024;
#pragma unroll
    for (int mt = 0; mt < 4; ++mt)
#pragma unroll
      for (int nt = 0; nt < 4; ++nt)
#pragma unroll
        for (int r = 0; r < 4; ++r) {
          size_t row = m0 + wm + mt * 16 + quad * 4 + r;
          size_t col = (size_t)(nl0 + wn + nt * 16 + l16);
          C[row * 1024 + col] = (__bf16)(acc[mt][nt][r] * s);
        }
  } else {
    // V region: write transposed vbT[(b*16+h)*64+d][sq] via chunked LDS staging.
    constexpr int LBS = 144;  // buf row stride (elems): 288B = 18*16B, aligned
    __bf16* bufA = As;        // 16*144 = 2304 elems <= 4096
    __bf16* bufB = Bs;
    __bf16* mybuf = (wid & 1) ? bufB : bufA;
    const int colbase = (int)n0 - 2048;
    const int b = (int)(m0 >> 11);
    const int sq0 = (int)(m0 & 2047);
#pragma unroll
    for (int c = 0; c < 4; ++c) {
#pragma unroll
      for (int mt = 0; mt < 4; ++mt) {
        union { __bf16 h[4]; uint2 u; } pk;
#pragma unroll
        for (int r = 0; r < 4; ++r) pk.h[r] = (__bf16)acc[mt][c][r];
        *(uint2*)&mybuf[l16 * LBS + wm + mt * 16 + quad * 4] = pk.u;
      }
      __syncthreads();
      {
        const int p = tid >> 7;
        const __bf16* rb = p ? bufB : bufA;
        const int d16 = (tid >> 3) & 15;
        const int sc = tid & 7;
        const int colg = colbase + p * 64 + c * 16 + d16;
        const int hh = colg >> 6, dd = colg & 63;
        const size_t rowb = ((size_t)b * 16 + hh) * 64 + dd;
        uint4 v0 = *(const uint4*)&rb[d16 * LBS + sc * 16];
        uint4 v1 = *(const uint4*)&rb[d16 * LBS + sc * 16 + 8];
        *(uint4*)&vbT[rowb * 2048 + sq0 + sc * 16] = v0;
        *(uint4*)&vbT[rowb * 2048 + sq0 + sc * 16 + 8] = v1;
      }
      __syncthreads();
    }
  }
}

// ---------------- final projection: out[8192][64] = ob @ WuT^T + bu ----------------
// BM=32, BK=64 -> 256 blocks (1/CU). Inline probe (reads x) replaces flag dep.
__global__ void __launch_bounds__(256)
gemm_out(const __bf16* __restrict__ A, const __bf16* __restrict__ Bt,
         void* __restrict__ Cv, const void* __restrict__ biasv,
         const unsigned short* __restrict__ xprobe) {
  constexpr int BK = 64, K = 1024, N = 64;
  __shared__ __attribute__((aligned(16))) __bf16 As[32 * BK];
  __shared__ __attribute__((aligned(16))) __bf16 Bs[64 * BK];
  __shared__ int sflag;

  const int tid = threadIdx.x;
  if (tid < 64) {
    int cnt = probe_cnt_wave(xprobe, tid);
    if (tid == 0) sflag = (cnt >= 512) ? 1 : 0;
  }
  // sflag is consumed only in the epilogue; the K-loop's barriers cover visibility.

  const int wid = tid >> 6, lane = tid & 63;
  const int quad = lane >> 4, l16 = lane & 15;
  const int wm = (wid >> 1) * 16, wn = (wid & 1) * 32;
  const size_t m0 = (size_t)blockIdx.x * 32;

  f32x4 acc[2];
  acc[0] = (f32x4){0.f, 0.f, 0.f, 0.f};
  acc[1] = (f32x4){0.f, 0.f, 0.f, 0.f};

  for (int k0 = 0; k0 < K; k0 += BK) {
    {  // A: 32 rows x 8 chunks = 256 slots
      int r = tid >> 3, c = (tid & 7) * 8;
      gld16(&A[(m0 + r) * K + k0 + c], &As[(tid & 192) * 8]);
    }
#pragma unroll
    for (int i = 0; i < 2; ++i) {  // B: 64 rows x 8 chunks = 512 slots
      int s = i * 256 + tid, r = s >> 3, c = (s & 7) * 8;
      gld16(&Bt[r * K + k0 + c], &Bs[(i * 256 + (tid & 192)) * 8]);
    }
    __syncthreads();

#pragma unroll
    for (int kc = 0; kc < 2; ++kc) {
      s16x8 af = *(const s16x8*)&As[(wm + l16) * BK + kc * 32 + quad * 8];
#pragma unroll
      for (int nt = 0; nt < 2; ++nt) {
        s16x8 bf = *(const s16x8*)&Bs[(wn + nt * 16 + l16) * BK + kc * 32 + quad * 8];
        acc[nt] = MFMA16(af, bf, acc[nt]);
      }
    }
    __syncthreads();
  }

  const bool raw_bf = (sflag != 0);
#pragma unroll
  for (int nt = 0; nt < 2; ++nt)
#pragma unroll
    for (int r = 0; r < 4; ++r) {
      size_t row = m0 + wm + quad * 4 + r;
      size_t col = (size_t)(wn + nt * 16 + l16);
      float v = acc[nt][r];
      v += raw_bf ? (float)((const __bf16*)biasv)[col] : ((const float*)biasv)[col];
      if (raw_bf) ((__bf16*)Cv)[row * N + col] = (__bf16)v;
      else        ((float*)Cv)[row * N + col] = v;
    }
}

// ---------------- round-2 dual-dtype GEMM (fallback for small ws) ----------------
template <int BM, int BN, bool BIAS, bool A_WS, bool C_WS>
__global__ void __launch_bounds__(256)
gemm_bt(const void* __restrict__ Av, const __bf16* __restrict__ Bt,
        void* __restrict__ Cv, const void* __restrict__ biasv,
        int M, int N, int K, float scale, const int* __restrict__ flag) {
  constexpr int BK = 32;
  constexpr int LDT = BK + 8;
  __shared__ __attribute__((aligned(16))) __bf16 As[BM][LDT];
  __shared__ __attribute__((aligned(16))) __bf16 Bs[BN][LDT];
  constexpr int WM = BM / 2, WN = BN / 2;
  constexpr int MT = WM / 16, NT = WN / 16;

  const bool raw_bf = (*flag != 0);
  const bool a_bf = A_WS ? true : raw_bf;

  const int tid = threadIdx.x;
  const int wid = tid >> 6, lane = tid & 63;
  const int quad = lane >> 4, l16 = lane & 15;
  const int wm = (wid >> 1) * WM, wn = (wid & 1) * WN;
  const size_t m0 = (size_t)blockIdx.x * BM;
  const size_t n0 = (size_t)blockIdx.y * BN;

  f32x4 acc[MT][NT];
#pragma unroll
  for (int i = 0; i < MT; ++i)
#pragma unroll
    for (int j = 0; j < NT; ++j) acc[i][j] = (f32x4){0.f, 0.f, 0.f, 0.f};

  for (int k0 = 0; k0 < K; k0 += BK) {
    if (a_bf) {
      const __bf16* A = (const __bf16*)Av;
#pragma unroll
      for (int i = 0; i < (BM * 4) / 256; ++i) {
        int s = i * 256 + tid, r = s >> 2, c = (s & 3) * 8;
        *(uint4*)&As[r][c] = *(const uint4*)&A[(m0 + r) * K + k0 + c];
      }
    } else {
      const float* A = (const float*)Av;
#pragma unroll
      for (int i = 0; i < (BM * 8) / 256; ++i) {
        int s = i * 256 + tid, r = s >> 3, c = (s & 7) * 4;
        float4 t = *(const float4*)&A[(m0 + r) * K + k0 + c];
        union { __bf16 h[4]; uint2 u; } cv;
        cv.h[0] = (__bf16)t.x; cv.h[1] = (__bf16)t.y;
        cv.h[2] = (__bf16)t.z; cv.h[3] = (__bf16)t.w;
        *(uint2*)&As[r][c] = cv.u;
      }
    }
#pragma unroll
    for (int i = 0; i < (BN * 4) / 256; ++i) {
      int s = i * 256 + tid, r = s >> 2, c = (s & 3) * 8;
      *(uint4*)&Bs[r][c] = *(const uint4*)&Bt[(n0 + r) * K + k0 + c];
    }
    __syncthreads();

    s16x8 af[MT], bf[NT];
#pragma unroll
    for (int mt = 0; mt < MT; ++mt)
      af[mt] = *(const s16x8*)&As[wm + mt * 16 + l16][quad * 8];
#pragma unroll
    for (int nt = 0; nt < NT; ++nt)
      bf[nt] = *(const s16x8*)&Bs[wn + nt * 16 + l16][quad * 8];
#pragma unroll
    for (int mt = 0; mt < MT; ++mt)
#pragma unroll
      for (int nt = 0; nt < NT; ++nt)
        acc[mt][nt] = MFMA16(af[mt], bf[nt], acc[mt][nt]);
    __syncthreads();
  }

#pragma unroll
  for (int mt = 0; mt < MT; ++mt)
#pragma unroll
    for (int nt = 0; nt < NT; ++nt)
#pragma unroll
      for (int r = 0; r < 4; ++r) {
        size_t row = m0 + wm + mt * 16 + quad * 4 + r;
        size_t col = n0 + wn + nt * 16 + l16;
        float v = acc[mt][nt][r] * scale;
        if (BIAS)
          v += raw_bf ? (float)((const __bf16*)biasv)[col] : ((const float*)biasv)[col];
        if (C_WS || raw_bf) ((__bf16*)Cv)[row * N + col] = (__bf16)v;
        else                ((float*)Cv)[row * N + col] = v;
      }
}

// ---------------- flash attention v9 (R4-proven): split-phase DMA, LDP=64 swizzled P ----
// 1-D grid 1024, 256 thr (4 waves, wave w owns q-rows [w*32,w*32+32)).
// xcd = id&7 serves bh in {xcd*8..xcd*8+7} -> KV tiles L2-resident.
// Structure floor ~86us established R4/R5 (V-dbuf null): MfmaUtil 35 + VALU 44,
// remainder is intra-wave dependency accounting. Do not re-tune without a
// structural change (32x32 MFMA or wave-specialization).
__global__ void __launch_bounds__(256, 4)
attn5_kernel(const __bf16* __restrict__ qg, const __bf16* __restrict__ kg,
             const __bf16* __restrict__ vtg, __bf16* __restrict__ og) {
  constexpr int SKV = 2048, QT = 128, KT = 64, SS = 1024, VS = 2048;
  __shared__ __attribute__((aligned(16))) __bf16 QP[QT * 64];   // Q [128][64] then P [128][64] swz
  __shared__ __attribute__((aligned(16))) __bf16 Ks[KT * 64];   // [key][d], XOR-src-swizzled
  __shared__ __attribute__((aligned(16))) __bf16 Vt[64 * KT];   // [d][key], XOR-src-swizzled

  const int tid = threadIdx.x;
  const int wid = tid >> 6, lane = tid & 63;
  const int quad = lane >> 4, l16 = lane & 15;

  const int id = blockIdx.x;
  const int j = id >> 3;
  const int bh = (id & 7) * 8 + (j & 7);
  const int b = bh >> 4, h = bh & 15;
  const int q0 = (j >> 3) * QT;

  const __bf16* qb = qg + (size_t)b * 2048 * SS + h * 64;
  const __bf16* kb = kg + (size_t)b * 2048 * SS + h * 64;
  const __bf16* vtb = vtg + (size_t)bh * 64 * VS;
  __bf16* ob = og + (size_t)b * 2048 * SS + h * 64;

#pragma unroll
  for (int i = 0; i < 4; ++i) {
    int s = i * 256 + tid, r = s >> 3, slot = s & 7, c = slot ^ (r & 7);
    gld16(&qb[(size_t)(q0 + r) * SS + c * 8], &QP[(i * 256 + (tid & 192)) * 8]);
  }
  __syncthreads();

  s16x8 qf[2][2];
#pragma unroll
  for (int nt = 0; nt < 2; ++nt)
#pragma unroll
    for (int kc = 0; kc < 2; ++kc) {
      int row = wid * 32 + nt * 16 + l16;
      qf[nt][kc] = *(const s16x8*)&QP[row * 64 + (((quad + kc * 4) ^ (row & 7)) * 8)];
    }
  __syncthreads();  // QP now reusable as P; also drains Q DMA fully

  // ---- hoist all loop-invariant LDS element offsets into registers ----
  // P layout: [row][64] with 8-elem-unit XOR swizzle: unit' = unit ^ (row&7).
  int koff[4][2];   // Ks read (kfa): [mtk][kc]
  int pwoff[2][4];  // P write: [ntq][mtk]  (b64 at unit'*8 + (quad&1)*4)
  int proff[2][2];  // P read (pf): [mt2][kc] (b128 at unit'*8)
  int voff[2][4];   // Vt read (vf): [kc][ntd]
#pragma unroll
  for (int mtk = 0; mtk < 4; ++mtk)
#pragma unroll
    for (int kc = 0; kc < 2; ++kc) {
      int row = mtk * 16 + l16;
      koff[mtk][kc] = row * 64 + (((quad + kc * 4) ^ (row & 7)) * 8);
    }
#pragma unroll
  for (int ntq = 0; ntq < 2; ++ntq) {
    int row = wid * 32 + ntq * 16 + l16;
#pragma unroll
    for (int mtk = 0; mtk < 4; ++mtk)
      pwoff[ntq][mtk] = row * 64 + (((2 * mtk + (quad >> 1)) ^ (row & 7)) * 8) + (quad & 1) * 4;
#pragma unroll
    for (int kc = 0; kc < 2; ++kc)
      proff[ntq][kc] = row * 64 + (((4 * kc + quad) ^ (row & 7)) * 8);
  }
#pragma unroll
  for (int kc = 0; kc < 2; ++kc)
#pragma unroll
    for (int ntd = 0; ntd < 4; ++ntd) {
      int d = ntd * 16 + l16;
      voff[kc][ntd] = d * 64 + (((kc * 4 + quad) ^ (d & 7)) * 8);
    }

  float lsum[2] = {0.f, 0.f};
  f32x4 oacc[2][4];
#pragma unroll
  for (int mt = 0; mt < 2; ++mt)
#pragma unroll
    for (int nt = 0; nt < 4; ++nt) oacc[mt][nt] = (f32x4){0.f, 0.f, 0.f, 0.f};

  // prologue: stage K(0)
#pragma unroll
  for (int i = 0; i < 2; ++i) {
    int s = i * 256 + tid, r = s >> 3, slot = s & 7, c = slot ^ (r & 7);
    gld16(&kb[(size_t)r * SS + c * 8], &Ks[(i * 256 + (tid & 192)) * 8]);
  }

  for (int kv = 0; kv < SKV; kv += KT) {
    // K(kv) landed (only its 2 loads outstanding); everyone done reading Vt(kv-KT)
    asm volatile("s_waitcnt vmcnt(0)" ::: "memory");
    __builtin_amdgcn_s_barrier();

    // stage V(kv) -> Vt; overlaps QK^T below (which reads only Ks)
#pragma unroll
    for (int i = 0; i < 2; ++i) {
      int s = i * 256 + tid, r = s >> 3, slot = s & 7, c = slot ^ (r & 7);
      gld16(&vtb[(size_t)r * VS + kv + c * 8], &Vt[(i * 256 + (tid & 192)) * 8]);
    }

    // S^T[key][q] = K·Q^T ; exp2 ; packed b64 P store (wave-private rows)
#pragma unroll
    for (int mtk = 0; mtk < 4; ++mtk) {
      s16x8 kfa[2];
#pragma unroll
      for (int kc = 0; kc < 2; ++kc)
        kfa[kc] = *(const s16x8*)&Ks[koff[mtk][kc]];
#pragma unroll
      for (int ntq = 0; ntq < 2; ++ntq) {
        f32x4 z = (f32x4){0.f, 0.f, 0.f, 0.f};
        __builtin_amdgcn_s_setprio(1);
        z = MFMA16(kfa[0], qf[ntq][0], z);
        z = MFMA16(kfa[1], qf[ntq][1], z);
        __builtin_amdgcn_s_setprio(0);
        union { __bf16 hh[4]; uint2 u; } pk;
        float p0 = fast_exp2(z[0]);
        float p1 = fast_exp2(z[1]);
        float p2 = fast_exp2(z[2]);
        float p3 = fast_exp2(z[3]);
        pk.hh[0] = (__bf16)p0; pk.hh[1] = (__bf16)p1;
        pk.hh[2] = (__bf16)p2; pk.hh[3] = (__bf16)p3;
        lsum[ntq] += (p0 + p1) + (p2 + p3);
        *(uint2*)&QP[pwoff[ntq][mtk]] = pk.u;
      }
    }

    // V(kv) landed (only its 2 loads outstanding); everyone done reading Ks(kv)
    asm volatile("s_waitcnt vmcnt(0)" ::: "memory");
    __builtin_amdgcn_s_barrier();

    // stage K(kv+KT) -> Ks; overlaps PV below (which reads only Vt + QP)
    if (kv + KT < SKV) {
#pragma unroll
      for (int i = 0; i < 2; ++i) {
        int s = i * 256 + tid, r = s >> 3, slot = s & 7, c = slot ^ (r & 7);
        gld16(&kb[(size_t)(kv + KT + r) * SS + c * 8], &Ks[(i * 256 + (tid & 192)) * 8]);
      }
    }

    // O += P·V  (P rows wave-private; per-wave LDS ops in-order)
#pragma unroll
    for (int kc = 0; kc < 2; ++kc) {
      s16x8 pf[2], vf[4];
#pragma unroll
      for (int mt2 = 0; mt2 < 2; ++mt2)
        pf[mt2] = *(const s16x8*)&QP[proff[mt2][kc]];
#pragma unroll
      for (int ntd = 0; ntd < 4; ++ntd)
        vf[ntd] = *(const s16x8*)&Vt[voff[kc][ntd]];
      __builtin_amdgcn_s_setprio(1);
#pragma unroll
      for (int mt2 = 0; mt2 < 2; ++mt2)
#pragma unroll
        for (int ntd = 0; ntd < 4; ++ntd)
          oacc[mt2][ntd] = MFMA16(pf[mt2], vf[ntd], oacc[mt2][ntd]);
      __builtin_amdgcn_s_setprio(0);
    }
  }

#pragma unroll
  for (int nt = 0; nt < 2; ++nt) {
    lsum[nt] += __shfl_xor(lsum[nt], 16);
    lsum[nt] += __shfl_xor(lsum[nt], 32);
  }
#pragma unroll
  for (int mt2 = 0; mt2 < 2; ++mt2)
#pragma unroll
    for (int r = 0; r < 4; ++r) {
      float l = __shfl(lsum[mt2], quad * 4 + r);
      float linv = 1.0f / l;
      int row = q0 + wid * 32 + mt2 * 16 + quad * 4 + r;
#pragma unroll
      for (int ntd = 0; ntd < 4; ++ntd)
        ob[(size_t)row * SS + ntd * 16 + l16] = (__bf16)(oacc[mt2][ntd][r] * linv);
    }
}

// ---------------- round-3 flash attention (fallback path, scalar V scatter) ----------------
__global__ void __launch_bounds__(256)
attn_kernel(const __bf16* __restrict__ qg, const __bf16* __restrict__ kg,
            const __bf16* __restrict__ vg, __bf16* __restrict__ og) {
  constexpr int D = 64, SKV = 2048, QT = 128, KT = 64, SS = 1024;
  constexpr int LDP = 72, LDV = 72;
  __shared__ __attribute__((aligned(16))) __bf16 QP[QT * LDP];
  __shared__ __attribute__((aligned(16))) __bf16 Ks[KT * D];
  __shared__ __attribute__((aligned(16))) __bf16 Vts[D * LDV];

  const int tid = threadIdx.x;
  const int wid = tid >> 6, lane = tid & 63;
  const int quad = lane >> 4, l16 = lane & 15;
  const int b = blockIdx.y >> 4, h = blockIdx.y & 15;
  const int q0 = blockIdx.x * QT;

  const __bf16* qb = qg + (size_t)b * 2048 * SS + h * D;
  const __bf16* kb = kg + (size_t)b * 2048 * SS + h * D;
  const __bf16* vb = vg + (size_t)b * 2048 * SS + h * D;
  __bf16* ob = og + (size_t)b * 2048 * SS + h * D;

#pragma unroll
  for (int i = 0; i < 4; ++i) {
    int s = i * 256 + tid, r = s >> 3, slot = s & 7, c = slot ^ (r & 7);
    gld16(&qb[(size_t)(q0 + r) * SS + c * 8], &QP[(i * 256 + (tid & 192)) * 8]);
  }
  __syncthreads();

  s16x8 qf[2][2];
#pragma unroll
  for (int nt = 0; nt < 2; ++nt)
#pragma unroll
    for (int kc = 0; kc < 2; ++kc) {
      int row = wid * 32 + nt * 16 + l16;
      qf[nt][kc] = *(const s16x8*)&QP[row * 64 + (((quad + kc * 4) ^ (row & 7)) * 8)];
    }
  __syncthreads();

  float lsum[2] = {0.f, 0.f};
  f32x4 oacc[2][4];
#pragma unroll
  for (int mt = 0; mt < 2; ++mt)
#pragma unroll
    for (int nt = 0; nt < 4; ++nt) oacc[mt][nt] = (f32x4){0.f, 0.f, 0.f, 0.f};

  for (int kv = 0; kv < SKV; kv += KT) {
#pragma unroll
    for (int i = 0; i < 2; ++i) {
      int s = i * 256 + tid, r = s >> 3, slot = s & 7, c = slot ^ (r & 7);
      gld16(&kb[(size_t)(kv + r) * SS + c * 8], &Ks[(i * 256 + (tid & 192)) * 8]);
    }
#pragma unroll
    for (int i = 0; i < 2; ++i) {
      int s = i * 256 + tid, r = s >> 3, mc = s & 7;
      uint4 t = *(const uint4*)&vb[(size_t)(kv + r) * SS + mc * 8];
      const __bf16* tp = (const __bf16*)&t;
      int colbase = r ^ (mc << 3);
#pragma unroll
      for (int jj = 0; jj < 8; ++jj) Vts[(mc * 8 + jj) * LDV + colbase] = tp[jj];
    }
    __syncthreads();

#pragma unroll
    for (int mtk = 0; mtk < 4; ++mtk) {
      s16x8 kfa[2];
#pragma unroll
      for (int kc = 0; kc < 2; ++kc) {
        int row = mtk * 16 + l16;
        kfa[kc] = *(const s16x8*)&Ks[row * 64 + (((quad + kc * 4) ^ (row & 7)) * 8)];
      }
#pragma unroll
      for (int ntq = 0; ntq < 2; ++ntq) {
        f32x4 z = (f32x4){0.f, 0.f, 0.f, 0.f};
        z = MFMA16(kfa[0], qf[ntq][0], z);
        z = MFMA16(kfa[1], qf[ntq][1], z);
        union { __bf16 hh[4]; uint2 u; } pk;
        float ps = 0.f;
#pragma unroll
        for (int r = 0; r < 4; ++r) {
          float p = __builtin_exp2f(fminf(z[r], 80.f));
          ps += p;
          pk.hh[r] = (__bf16)p;
        }
        lsum[ntq] += ps;
        int row = wid * 32 + ntq * 16 + l16;
        *(uint2*)&QP[row * LDP + mtk * 16 + quad * 4] = pk.u;
      }
    }

#pragma unroll
    for (int kc = 0; kc < 2; ++kc) {
      s16x8 pf[2], vf[4];
#pragma unroll
      for (int mt2 = 0; mt2 < 2; ++mt2)
        pf[mt2] = *(const s16x8*)&QP[(wid * 32 + mt2 * 16 + l16) * LDP + kc * 32 + quad * 8];
#pragma unroll
      for (int ntd = 0; ntd < 4; ++ntd) {
        int d = ntd * 16 + l16;
        int col0 = (kc * 32 + quad * 8) ^ ((((d >> 3) & 7)) << 3);
        vf[ntd] = *(const s16x8*)&Vts[d * LDV + col0];
      }
#pragma unroll
      for (int mt2 = 0; mt2 < 2; ++mt2)
#pragma unroll
        for (int ntd = 0; ntd < 4; ++ntd)
          oacc[mt2][ntd] = MFMA16(pf[mt2], vf[ntd], oacc[mt2][ntd]);
    }
    __syncthreads();
  }

#pragma unroll
  for (int nt = 0; nt < 2; ++nt) {
    lsum[nt] += __shfl_xor(lsum[nt], 16);
    lsum[nt] += __shfl_xor(lsum[nt], 32);
  }
#pragma unroll
  for (int mt2 = 0; mt2 < 2; ++mt2)
#pragma unroll
    for (int r = 0; r < 4; ++r) {
      float l = __shfl(lsum[mt2], quad * 4 + r);
      float linv = 1.0f / l;
      int row = q0 + wid * 32 + mt2 * 16 + quad * 4 + r;
#pragma unroll
      for (int ntd = 0; ntd < 4; ++ntd)
        ob[(size_t)row * SS + ntd * 16 + l16] = (__bf16)(oacc[mt2][ntd][r] * linv);
    }
}

// ---------------- launch ----------------
extern "C" void kernel_launch(void* const* d_in, const int* in_sizes, int n_in,
                              void* d_out, int out_size, void* d_ws, size_t ws_size,
                              hipStream_t stream) {
  const void* x  = d_in[0];  // [4,2048,1024]
  const void* y  = d_in[1];
  const void* Wv = d_in[2];  // [1024,1024] (in,out)
  const void* Wk = d_in[3];
  const void* Wq = d_in[4];
  const void* Wu = d_in[5];  // [1024,64]
  const void* bu = d_in[6];  // [64]

  const float sc  = 0.17677669529663687f;                        // 1024^-0.25
  const float scq = 0.17677669529663687f * 1.4426950408889634f;  // + log2(e) fold

  constexpr size_t NTOK = (size_t)8192 * 1024;
  constexpr size_t TB = NTOK * 2;

  char* p = (char*)d_ws;
  int* flag = (int*)p; p += 256;
  __bf16* qb = (__bf16*)p; p += TB;
  __bf16* kb = (__bf16*)p; p += TB;
  __bf16* vb = (__bf16*)p; p += TB;   // fast path: used as vbT
  __bf16* WuT = (__bf16*)p; p += (size_t)64 * 1024 * 2;

  const size_t fast_need = 256 + 3 * TB + (size_t)64 * 1024 * 2 + 2 * TB + 3 * (size_t)1024 * 1024 * 2;
  if (ws_size >= fast_need) {
    __bf16* xb = (__bf16*)p; p += TB;
    __bf16* yb = (__bf16*)p; p += TB;
    __bf16* WqkvT = (__bf16*)p;  // 3 x [1024][1024]
    __bf16* vbT = vb;
    __bf16* ob  = xb;  // xb dead after gemm_qkv

    pre_kernel<<<dim3(5184), 256, 0, stream>>>(x, y, Wq, Wk, Wv, Wu, xb, yb, WqkvT, WuT);

    gemm_qkv<<<dim3(1536), 256, 0, stream>>>(xb, yb, WqkvT, qb, kb, vbT, scq, sc);

    attn5_kernel<<<dim3(1024), 256, 0, stream>>>(qb, kb, vbT, ob);

    gemm_out<<<dim3(256), 256, 0, stream>>>(ob, WuT, d_out, bu, (const unsigned short*)x);
  } else {
    __bf16* region = (__bf16*)p;
    __bf16* WqT = region;
    __bf16* WkT = region + (size_t)1024 * 1024;
    __bf16* WvT = region + (size_t)2 * 1024 * 1024;
    __bf16* ob  = region;

    probe_kernel<<<1, 64, 0, stream>>>((const unsigned short*)x, flag);
    tr3_kernel<<<dim3(32, 32, 4), 256, 0, stream>>>(Wq, Wk, Wv, Wu, WqT, WuT, flag);

    gemm_bt<128, 128, false, false, true><<<dim3(64, 8), 256, 0, stream>>>(
        y, WqT, qb, nullptr, 8192, 1024, 1024, scq, flag);
    gemm_bt<128, 128, false, false, true><<<dim3(64, 8), 256, 0, stream>>>(
        x, WkT, kb, nullptr, 8192, 1024, 1024, sc, flag);
    gemm_bt<128, 128, false, false, true><<<dim3(64, 8), 256, 0, stream>>>(
        x, WvT, vb, nullptr, 8192, 1024, 1024, 1.0f, flag);

    attn_kernel<<<dim3(16, 64), 256, 0, stream>>>(qb, kb, vb, ob);

    gemm_bt<128, 64, true, true, false><<<dim3(64, 1), 256, 0, stream>>>(
        ob, WuT, d_out, bu, 8192, 64, 1024, 1.0f, flag);
  }
}

// Round 7
// 275.192 us; speedup vs baseline: 1.0179x; 1.0047x over previous
//
#include <hip/hip_runtime.h>
#include <hip/hip_bf16.h>
#include <stdint.h>

typedef short s16x8 __attribute__((ext_vector_type(8)));   // 8 bf16 bits (4 VGPRs)
typedef float f32x4 __attribute__((ext_vector_type(4)));

#define MFMA16(a, b, c) __builtin_amdgcn_mfma_f32_16x16x32_bf16((a), (b), (c), 0, 0, 0)

// async global->LDS, 16B per lane. LDS dest must be wave-uniform; HW adds lane*16.
__device__ __forceinline__ void gld16(const __bf16* g, __bf16* l) {
  __builtin_amdgcn_global_load_lds(
      (const __attribute__((address_space(1))) unsigned int*)g,
      (__attribute__((address_space(3))) unsigned int*)l, 16, 0, 0);
}

// raw v_exp_f32: skip LLVM's denormal-input range-fixup sequence (~5 VALU/exp).
__device__ __forceinline__ float fast_exp2(float x) {
#if __has_builtin(__builtin_amdgcn_exp2f)
  return __builtin_amdgcn_exp2f(x);
#else
  float r;
  asm("v_exp_f32 %0, %1" : "=v"(r) : "v"(x));
  return r;
#endif
}

// probe logic: sample 1024 interleaved shorts of x; if they decode to sane bf16,
// input is bf16, else f32. Deterministic -> every block computes the same answer.
__device__ __forceinline__ int probe_cnt_wave(const unsigned short* xs, int lane) {
  int cnt = 0;
  for (int i = lane; i < 1024; i += 64) {
    unsigned bits = ((unsigned)xs[2 * i]) << 16;
    float f = __uint_as_float(bits);
    float a = fabsf(f);
    if (f == f && a >= 1e-4f && a <= 1e4f) cnt++;
  }
#pragma unroll
  for (int off = 32; off; off >>= 1) cnt += __shfl_down(cnt, off);
  return cnt;  // valid in lane 0
}

// ---------------- dtype probe kernel (fallback path only) ----------------
__global__ void probe_kernel(const unsigned short* __restrict__ x, int* __restrict__ flag) {
  int cnt = probe_cnt_wave(x, threadIdx.x & 63);
  if (threadIdx.x == 0) *flag = (cnt >= 512) ? 1 : 0;
}

// ---------------- fused pre-kernel: inline probe + cvt(x,y)->bf16 + 4 weight transposes ----
// grid 5184 x 256: blocks [0,2048) convert x,y; blocks [2048,5184) transpose
// Wq/Wk/Wv (z=0..2, 1024 blocks each) and Wu (z=3, 64 blocks).
__global__ void __launch_bounds__(256)
pre_kernel(const void* __restrict__ x, const void* __restrict__ y,
           const void* __restrict__ w0, const void* __restrict__ w1,
           const void* __restrict__ w2, const void* __restrict__ w3,
           __bf16* __restrict__ xb, __bf16* __restrict__ yb,
           __bf16* __restrict__ wqkvT, __bf16* __restrict__ wuT) {
  __shared__ int sflag;
  __shared__ float tile[32][33];
  if (threadIdx.x < 64) {
    int cnt = probe_cnt_wave((const unsigned short*)x, threadIdx.x);
    if (threadIdx.x == 0) sflag = (cnt >= 512) ? 1 : 0;
  }
  __syncthreads();
  const bool isbf = (sflag != 0);

  const int bid = blockIdx.x;
  if (bid < 2048) {
    constexpr int NV = (int)((size_t)8192 * 1024 / 8);  // vectors of 8 per tensor
    int i = bid * 256 + threadIdx.x;
    const int stride = 2048 * 256;
    for (; i < 2 * NV; i += stride) {
      int v = (i < NV) ? i : i - NV;
      const void* in = (i < NV) ? x : y;
      __bf16* out = (i < NV) ? xb : yb;
      if (isbf) {
        *(uint4*)&out[v * 8] = *(const uint4*)&((const __bf16*)in)[v * 8];
      } else {
        float4 a = *(const float4*)&((const float*)in)[v * 8];
        float4 b = *(const float4*)&((const float*)in)[v * 8 + 4];
        union { __bf16 h[8]; uint4 u; } pk;
        pk.h[0] = (__bf16)a.x; pk.h[1] = (__bf16)a.y; pk.h[2] = (__bf16)a.z; pk.h[3] = (__bf16)a.w;
        pk.h[4] = (__bf16)b.x; pk.h[5] = (__bf16)b.y; pk.h[6] = (__bf16)b.z; pk.h[7] = (__bf16)b.w;
        *(uint4*)&out[v * 8] = pk.u;
      }
    }
  } else {
    int t = bid - 2048;
    int z, bx, by;
    if (t < 3072) { z = t >> 10; int xy = t & 1023; bx = xy & 31; by = xy >> 5; }
    else          { z = 3; int u = t - 3072; bx = u & 1; by = u >> 1; }
    const void* in = (z == 0) ? w0 : (z == 1) ? w1 : (z == 2) ? w2 : w3;
    __bf16* out = (z == 3) ? wuT : wqkvT + (size_t)z * 1024 * 1024;
    const int N = (z == 3) ? 64 : 1024;
    int tx = threadIdx.x & 31, ty = threadIdx.x >> 5;
    int n0 = bx * 32, k0 = by * 32;
#pragma unroll
    for (int i = 0; i < 32; i += 8) {
      size_t idx = (size_t)(k0 + ty + i) * N + (n0 + tx);
      tile[ty + i][tx] = isbf ? (float)((const __bf16*)in)[idx] : ((const float*)in)[idx];
    }
    __syncthreads();
#pragma unroll
    for (int i = 0; i < 32; i += 8)
      out[(size_t)(n0 + ty + i) * 1024 + (k0 + tx)] = (__bf16)tile[tx][ty + i];
  }
}

// ---------------- 4 weight transposes (flag version, fallback path) ----------------
__global__ void tr3_kernel(const void* __restrict__ w0, const void* __restrict__ w1,
                           const void* __restrict__ w2, const void* __restrict__ w3,
                           __bf16* __restrict__ outbase, __bf16* __restrict__ out3,
                           const int* __restrict__ flag) {
  const bool isbf = (*flag != 0);
  const int z = blockIdx.z;
  if (z == 3 && blockIdx.x >= 2) return;
  const void* in = (z == 0) ? w0 : (z == 1) ? w1 : (z == 2) ? w2 : w3;
  __bf16* out = (z == 3) ? out3 : outbase + (size_t)z * 1024 * 1024;
  const int N = (z == 3) ? 64 : 1024;
  __shared__ float tile[32][33];
  int tx = threadIdx.x & 31, ty = threadIdx.x >> 5;
  int n0 = blockIdx.x * 32, k0 = blockIdx.y * 32;
#pragma unroll
  for (int i = 0; i < 32; i += 8) {
    size_t idx = (size_t)(k0 + ty + i) * N + (n0 + tx);
    tile[ty + i][tx] = isbf ? (float)((const __bf16*)in)[idx] : ((const float*)in)[idx];
  }
  __syncthreads();
#pragma unroll
  for (int i = 0; i < 32; i += 8)
    out[(size_t)(n0 + ty + i) * 1024 + (k0 + tx)] = (__bf16)tile[tx][ty + i];
}

// ---------------- fused q/k/v projection GEMM, XCD-swizzled, K-dbuf pipeline ----------------
// 1-D grid of 1536. xcd = id&7 owns n-tiles {3*xcd..3*xcd+2}; j=id>>3 sweeps
// (m outer, n inner) so 3 consecutive blocks reuse each A tile from L2.
// n-tile ny: 0..7 -> q (A=yb, scale scq), 8..15 -> k (A=xb, sck),
//            16..23 -> v (A=xb, dst vbT transposed via LDS round-trip).
// R7 change: K-loop double-buffer (As/Bs x2, LDS 16->32KB, 5 blocks/CU was 6).
// Old loop: issue 4 DMA -> syncthreads (vmcnt-0 drain with ZERO compute cover)
// -> MFMA -> barrier. New: one vmcnt(0)+barrier per K-step waits for tile t
// (issued a full compute phase ago); tile t+1 DMA issues right after, covered
// by 16 MFMAs. Same transform that took attn 117->86us (R2). Race proof:
// buf[cur^1] reads completed before top barrier (lgkmcnt before MFMA, MFMA
// before barrier in program order); t+1 stores issue only after it.
__global__ void __launch_bounds__(256)
gemm_qkv(const __bf16* __restrict__ xb, const __bf16* __restrict__ yb,
         const __bf16* __restrict__ Wt,
         __bf16* __restrict__ qb, __bf16* __restrict__ kb, __bf16* __restrict__ vbT,
         float scq, float sck) {
  constexpr int BM = 128, BN = 128, BK = 32, K = 1024;
  __shared__ __attribute__((aligned(16))) __bf16 As[2][BM * BK];
  __shared__ __attribute__((aligned(16))) __bf16 Bs[2][BN * BK];

  const int tid = threadIdx.x;
  const int wid = tid >> 6, lane = tid & 63;
  const int quad = lane >> 4, l16 = lane & 15;
  const int wm = (wid >> 1) * 64, wn = (wid & 1) * 64;

  const int id = blockIdx.x;
  const int jj = id >> 3;
  const int ny = (id & 7) * 3 + (jj % 3);
  const int mb = jj / 3;
  const size_t m0 = (size_t)mb * BM;
  const size_t n0 = (size_t)ny * BN;
  const __bf16* A = (ny < 8) ? yb : xb;

  f32x4 acc[4][4];
#pragma unroll
  for (int i = 0; i < 4; ++i)
#pragma unroll
    for (int j = 0; j < 4; ++j) acc[i][j] = (f32x4){0.f, 0.f, 0.f, 0.f};

  // prologue: stage K-tile 0 into buffer 0
#pragma unroll
  for (int i = 0; i < 2; ++i) {
    int s = i * 256 + tid, r = s >> 2, c = (s & 3) * 8;
    gld16(&A[(m0 + r) * K + c], &As[0][(i * 256 + (tid & 192)) * 8]);
  }
#pragma unroll
  for (int i = 0; i < 2; ++i) {
    int s = i * 256 + tid, r = s >> 2, c = (s & 3) * 8;
    gld16(&Wt[(n0 + r) * K + c], &Bs[0][(i * 256 + (tid & 192)) * 8]);
  }

  for (int k0 = 0; k0 < K; k0 += BK) {
    const int cur = (k0 >> 5) & 1;
    // tile(k0) landed (its 4 loads are the only outstanding); all waves done
    // reading buf[cur^1] from the previous iteration.
    asm volatile("s_waitcnt vmcnt(0)" ::: "memory");
    __builtin_amdgcn_s_barrier();
    asm volatile("" ::: "memory");

    // stage tile(k0+BK) into the other buffer; 16 MFMAs below cover its latency
    if (k0 + BK < K) {
#pragma unroll
      for (int i = 0; i < 2; ++i) {
        int s = i * 256 + tid, r = s >> 2, c = (s & 3) * 8;
        gld16(&A[(m0 + r) * K + k0 + BK + c], &As[cur ^ 1][(i * 256 + (tid & 192)) * 8]);
      }
#pragma unroll
      for (int i = 0; i < 2; ++i) {
        int s = i * 256 + tid, r = s >> 2, c = (s & 3) * 8;
        gld16(&Wt[(n0 + r) * K + k0 + BK + c], &Bs[cur ^ 1][(i * 256 + (tid & 192)) * 8]);
      }
    }

    s16x8 af[4], bf[4];
#pragma unroll
    for (int mt = 0; mt < 4; ++mt)
      af[mt] = *(const s16x8*)&As[cur][(wm + mt * 16 + l16) * BK + quad * 8];
#pragma unroll
    for (int nt = 0; nt < 4; ++nt)
      bf[nt] = *(const s16x8*)&Bs[cur][(wn + nt * 16 + l16) * BK + quad * 8];
#pragma unroll
    for (int mt = 0; mt < 4; ++mt)
#pragma unroll
      for (int nt = 0; nt < 4; ++nt)
        acc[mt][nt] = MFMA16(af[mt], bf[nt], acc[mt][nt]);
  }

  if (ny < 16) {
    const float s = (ny < 8) ? scq : sck;
    __bf16* C = (ny < 8) ? qb : kb;
    const int nl0 = (ny < 8) ? (int)n0 : (int)n0 - 1024;
#pragma unroll
    for (int mt = 0; mt < 4; ++mt)
#pragma unroll
      for (int nt = 0; nt < 4; ++nt)
#pragma unroll
        for (int r = 0; r < 4; ++r) {
          size_t row = m0 + wm + mt * 16 + quad * 4 + r;
          size_t col = (size_t)(nl0 + wn + nt * 16 + l16);
          C[row * 1024 + col] = (__bf16)(acc[mt][nt][r] * s);
        }
  } else {
    // V region: write transposed vbT[(b*16+h)*64+d][sq] via chunked LDS staging.
    __syncthreads();  // all waves done with final K-tile ds_reads before LDS reuse
    constexpr int LBS = 144;  // buf row stride (elems): 288B = 18*16B, aligned
    __bf16* bufA = As[0];     // 16*144 = 2304 elems <= 4096
    __bf16* bufB = Bs[0];
    __bf16* mybuf = (wid & 1) ? bufB : bufA;
    const int colbase = (int)n0 - 2048;
    const int b = (int)(m0 >> 11);
    const int sq0 = (int)(m0 & 2047);
#pragma unroll
    for (int c = 0; c < 4; ++c) {
#pragma unroll
      for (int mt = 0; mt < 4; ++mt) {
        union { __bf16 h[4]; uint2 u; } pk;
#pragma unroll
        for (int r = 0; r < 4; ++r) pk.h[r] = (__bf16)acc[mt][c][r];
        *(uint2*)&mybuf[l16 * LBS + wm + mt * 16 + quad * 4] = pk.u;
      }
      __syncthreads();
      {
        const int p = tid >> 7;
        const __bf16* rb = p ? bufB : bufA;
        const int d16 = (tid >> 3) & 15;
        const int sc = tid & 7;
        const int colg = colbase + p * 64 + c * 16 + d16;
        const int hh = colg >> 6, dd = colg & 63;
        const size_t rowb = ((size_t)b * 16 + hh) * 64 + dd;
        uint4 v0 = *(const uint4*)&rb[d16 * LBS + sc * 16];
        uint4 v1 = *(const uint4*)&rb[d16 * LBS + sc * 16 + 8];
        *(uint4*)&vbT[rowb * 2048 + sq0 + sc * 16] = v0;
        *(uint4*)&vbT[rowb * 2048 + sq0 + sc * 16 + 8] = v1;
      }
      __syncthreads();
    }
  }
}

// ---------------- final projection: out[8192][64] = ob @ WuT^T + bu ----------------
// BM=32, BK=64 -> 256 blocks (1/CU). Inline probe (reads x) replaces flag dep.
__global__ void __launch_bounds__(256)
gemm_out(const __bf16* __restrict__ A, const __bf16* __restrict__ Bt,
         void* __restrict__ Cv, const void* __restrict__ biasv,
         const unsigned short* __restrict__ xprobe) {
  constexpr int BK = 64, K = 1024, N = 64;
  __shared__ __attribute__((aligned(16))) __bf16 As[32 * BK];
  __shared__ __attribute__((aligned(16))) __bf16 Bs[64 * BK];
  __shared__ int sflag;

  const int tid = threadIdx.x;
  if (tid < 64) {
    int cnt = probe_cnt_wave(xprobe, tid);
    if (tid == 0) sflag = (cnt >= 512) ? 1 : 0;
  }
  // sflag is consumed only in the epilogue; the K-loop's barriers cover visibility.

  const int wid = tid >> 6, lane = tid & 63;
  const int quad = lane >> 4, l16 = lane & 15;
  const int wm = (wid >> 1) * 16, wn = (wid & 1) * 32;
  const size_t m0 = (size_t)blockIdx.x * 32;

  f32x4 acc[2];
  acc[0] = (f32x4){0.f, 0.f, 0.f, 0.f};
  acc[1] = (f32x4){0.f, 0.f, 0.f, 0.f};

  for (int k0 = 0; k0 < K; k0 += BK) {
    {  // A: 32 rows x 8 chunks = 256 slots
      int r = tid >> 3, c = (tid & 7) * 8;
      gld16(&A[(m0 + r) * K + k0 + c], &As[(tid & 192) * 8]);
    }
#pragma unroll
    for (int i = 0; i < 2; ++i) {  // B: 64 rows x 8 chunks = 512 slots
      int s = i * 256 + tid, r = s >> 3, c = (s & 7) * 8;
      gld16(&Bt[r * K + k0 + c], &Bs[(i * 256 + (tid & 192)) * 8]);
    }
    __syncthreads();

#pragma unroll
    for (int kc = 0; kc < 2; ++kc) {
      s16x8 af = *(const s16x8*)&As[(wm + l16) * BK + kc * 32 + quad * 8];
#pragma unroll
      for (int nt = 0; nt < 2; ++nt) {
        s16x8 bf = *(const s16x8*)&Bs[(wn + nt * 16 + l16) * BK + kc * 32 + quad * 8];
        acc[nt] = MFMA16(af, bf, acc[nt]);
      }
    }
    __syncthreads();
  }

  const bool raw_bf = (sflag != 0);
#pragma unroll
  for (int nt = 0; nt < 2; ++nt)
#pragma unroll
    for (int r = 0; r < 4; ++r) {
      size_t row = m0 + wm + quad * 4 + r;
      size_t col = (size_t)(wn + nt * 16 + l16);
      float v = acc[nt][r];
      v += raw_bf ? (float)((const __bf16*)biasv)[col] : ((const float*)biasv)[col];
      if (raw_bf) ((__bf16*)Cv)[row * N + col] = (__bf16)v;
      else        ((float*)Cv)[row * N + col] = v;
    }
}

// ---------------- round-2 dual-dtype GEMM (fallback for small ws) ----------------
template <int BM, int BN, bool BIAS, bool A_WS, bool C_WS>
__global__ void __launch_bounds__(256)
gemm_bt(const void* __restrict__ Av, const __bf16* __restrict__ Bt,
        void* __restrict__ Cv, const void* __restrict__ biasv,
        int M, int N, int K, float scale, const int* __restrict__ flag) {
  constexpr int BK = 32;
  constexpr int LDT = BK + 8;
  __shared__ __attribute__((aligned(16))) __bf16 As[BM][LDT];
  __shared__ __attribute__((aligned(16))) __bf16 Bs[BN][LDT];
  constexpr int WM = BM / 2, WN = BN / 2;
  constexpr int MT = WM / 16, NT = WN / 16;

  const bool raw_bf = (*flag != 0);
  const bool a_bf = A_WS ? true : raw_bf;

  const int tid = threadIdx.x;
  const int wid = tid >> 6, lane = tid & 63;
  const int quad = lane >> 4, l16 = lane & 15;
  const int wm = (wid >> 1) * WM, wn = (wid & 1) * WN;
  const size_t m0 = (size_t)blockIdx.x * BM;
  const size_t n0 = (size_t)blockIdx.y * BN;

  f32x4 acc[MT][NT];
#pragma unroll
  for (int i = 0; i < MT; ++i)
#pragma unroll
    for (int j = 0; j < NT; ++j) acc[i][j] = (f32x4){0.f, 0.f, 0.f, 0.f};

  for (int k0 = 0; k0 < K; k0 += BK) {
    if (a_bf) {
      const __bf16* A = (const __bf16*)Av;
#pragma unroll
      for (int i = 0; i < (BM * 4) / 256; ++i) {
        int s = i * 256 + tid, r = s >> 2, c = (s & 3) * 8;
        *(uint4*)&As[r][c] = *(const uint4*)&A[(m0 + r) * K + k0 + c];
      }
    } else {
      const float* A = (const float*)Av;
#pragma unroll
      for (int i = 0; i < (BM * 8) / 256; ++i) {
        int s = i * 256 + tid, r = s >> 3, c = (s & 7) * 4;
        float4 t = *(const float4*)&A[(m0 + r) * K + k0 + c];
        union { __bf16 h[4]; uint2 u; } cv;
        cv.h[0] = (__bf16)t.x; cv.h[1] = (__bf16)t.y;
        cv.h[2] = (__bf16)t.z; cv.h[3] = (__bf16)t.w;
        *(uint2*)&As[r][c] = cv.u;
      }
    }
#pragma unroll
    for (int i = 0; i < (BN * 4) / 256; ++i) {
      int s = i * 256 + tid, r = s >> 2, c = (s & 3) * 8;
      *(uint4*)&Bs[r][c] = *(const uint4*)&Bt[(n0 + r) * K + k0 + c];
    }
    __syncthreads();

    s16x8 af[MT], bf[NT];
#pragma unroll
    for (int mt = 0; mt < MT; ++mt)
      af[mt] = *(const s16x8*)&As[wm + mt * 16 + l16][quad * 8];
#pragma unroll
    for (int nt = 0; nt < NT; ++nt)
      bf[nt] = *(const s16x8*)&Bs[wn + nt * 16 + l16][quad * 8];
#pragma unroll
    for (int mt = 0; mt < MT; ++mt)
#pragma unroll
      for (int nt = 0; nt < NT; ++nt)
        acc[mt][nt] = MFMA16(af[mt], bf[nt], acc[mt][nt]);
    __syncthreads();
  }

#pragma unroll
  for (int mt = 0; mt < MT; ++mt)
#pragma unroll
    for (int nt = 0; nt < NT; ++nt)
#pragma unroll
      for (int r = 0; r < 4; ++r) {
        size_t row = m0 + wm + mt * 16 + quad * 4 + r;
        size_t col = n0 + wn + nt * 16 + l16;
        float v = acc[mt][nt][r] * scale;
        if (BIAS)
          v += raw_bf ? (float)((const __bf16*)biasv)[col] : ((const float*)biasv)[col];
        if (C_WS || raw_bf) ((__bf16*)Cv)[row * N + col] = (__bf16)v;
        else                ((float*)Cv)[row * N + col] = v;
      }
}

// ---------------- flash attention v9 (R4-proven): split-phase DMA, LDP=64 swizzled P ----
// 1-D grid 1024, 256 thr (4 waves, wave w owns q-rows [w*32,w*32+32)).
// xcd = id&7 serves bh in {xcd*8..xcd*8+7} -> KV tiles L2-resident.
// Structure floor ~86us established R4/R5 (V-dbuf null): MfmaUtil 35 + VALU 44,
// remainder is intra-wave dependency accounting. Do not re-tune without a
// structural change (32x32 MFMA or wave-specialization).
__global__ void __launch_bounds__(256, 4)
attn5_kernel(const __bf16* __restrict__ qg, const __bf16* __restrict__ kg,
             const __bf16* __restrict__ vtg, __bf16* __restrict__ og) {
  constexpr int SKV = 2048, QT = 128, KT = 64, SS = 1024, VS = 2048;
  __shared__ __attribute__((aligned(16))) __bf16 QP[QT * 64];   // Q [128][64] then P [128][64] swz
  __shared__ __attribute__((aligned(16))) __bf16 Ks[KT * 64];   // [key][d], XOR-src-swizzled
  __shared__ __attribute__((aligned(16))) __bf16 Vt[64 * KT];   // [d][key], XOR-src-swizzled

  const int tid = threadIdx.x;
  const int wid = tid >> 6, lane = tid & 63;
  const int quad = lane >> 4, l16 = lane & 15;

  const int id = blockIdx.x;
  const int j = id >> 3;
  const int bh = (id & 7) * 8 + (j & 7);
  const int b = bh >> 4, h = bh & 15;
  const int q0 = (j >> 3) * QT;

  const __bf16* qb = qg + (size_t)b * 2048 * SS + h * 64;
  const __bf16* kb = kg + (size_t)b * 2048 * SS + h * 64;
  const __bf16* vtb = vtg + (size_t)bh * 64 * VS;
  __bf16* ob = og + (size_t)b * 2048 * SS + h * 64;

#pragma unroll
  for (int i = 0; i < 4; ++i) {
    int s = i * 256 + tid, r = s >> 3, slot = s & 7, c = slot ^ (r & 7);
    gld16(&qb[(size_t)(q0 + r) * SS + c * 8], &QP[(i * 256 + (tid & 192)) * 8]);
  }
  __syncthreads();

  s16x8 qf[2][2];
#pragma unroll
  for (int nt = 0; nt < 2; ++nt)
#pragma unroll
    for (int kc = 0; kc < 2; ++kc) {
      int row = wid * 32 + nt * 16 + l16;
      qf[nt][kc] = *(const s16x8*)&QP[row * 64 + (((quad + kc * 4) ^ (row & 7)) * 8)];
    }
  __syncthreads();  // QP now reusable as P; also drains Q DMA fully

  // ---- hoist all loop-invariant LDS element offsets into registers ----
  // P layout: [row][64] with 8-elem-unit XOR swizzle: unit' = unit ^ (row&7).
  int koff[4][2];   // Ks read (kfa): [mtk][kc]
  int pwoff[2][4];  // P write: [ntq][mtk]  (b64 at unit'*8 + (quad&1)*4)
  int proff[2][2];  // P read (pf): [mt2][kc] (b128 at unit'*8)
  int voff[2][4];   // Vt read (vf): [kc][ntd]
#pragma unroll
  for (int mtk = 0; mtk < 4; ++mtk)
#pragma unroll
    for (int kc = 0; kc < 2; ++kc) {
      int row = mtk * 16 + l16;
      koff[mtk][kc] = row * 64 + (((quad + kc * 4) ^ (row & 7)) * 8);
    }
#pragma unroll
  for (int ntq = 0; ntq < 2; ++ntq) {
    int row = wid * 32 + ntq * 16 + l16;
#pragma unroll
    for (int mtk = 0; mtk < 4; ++mtk)
      pwoff[ntq][mtk] = row * 64 + (((2 * mtk + (quad >> 1)) ^ (row & 7)) * 8) + (quad & 1) * 4;
#pragma unroll
    for (int kc = 0; kc < 2; ++kc)
      proff[ntq][kc] = row * 64 + (((4 * kc + quad) ^ (row & 7)) * 8);
  }
#pragma unroll
  for (int kc = 0; kc < 2; ++kc)
#pragma unroll
    for (int ntd = 0; ntd < 4; ++ntd) {
      int d = ntd * 16 + l16;
      voff[kc][ntd] = d * 64 + (((kc * 4 + quad) ^ (d & 7)) * 8);
    }

  float lsum[2] = {0.f, 0.f};
  f32x4 oacc[2][4];
#pragma unroll
  for (int mt = 0; mt < 2; ++mt)
#pragma unroll
    for (int nt = 0; nt < 4; ++nt) oacc[mt][nt] = (f32x4){0.f, 0.f, 0.f, 0.f};

  // prologue: stage K(0)
#pragma unroll
  for (int i = 0; i < 2; ++i) {
    int s = i * 256 + tid, r = s >> 3, slot = s & 7, c = slot ^ (r & 7);
    gld16(&kb[(size_t)r * SS + c * 8], &Ks[(i * 256 + (tid & 192)) * 8]);
  }

  for (int kv = 0; kv < SKV; kv += KT) {
    // K(kv) landed (only its 2 loads outstanding); everyone done reading Vt(kv-KT)
    asm volatile("s_waitcnt vmcnt(0)" ::: "memory");
    __builtin_amdgcn_s_barrier();

    // stage V(kv) -> Vt; overlaps QK^T below (which reads only Ks)
#pragma unroll
    for (int i = 0; i < 2; ++i) {
      int s = i * 256 + tid, r = s >> 3, slot = s & 7, c = slot ^ (r & 7);
      gld16(&vtb[(size_t)r * VS + kv + c * 8], &Vt[(i * 256 + (tid & 192)) * 8]);
    }

    // S^T[key][q] = K·Q^T ; exp2 ; packed b64 P store (wave-private rows)
#pragma unroll
    for (int mtk = 0; mtk < 4; ++mtk) {
      s16x8 kfa[2];
#pragma unroll
      for (int kc = 0; kc < 2; ++kc)
        kfa[kc] = *(const s16x8*)&Ks[koff[mtk][kc]];
#pragma unroll
      for (int ntq = 0; ntq < 2; ++ntq) {
        f32x4 z = (f32x4){0.f, 0.f, 0.f, 0.f};
        __builtin_amdgcn_s_setprio(1);
        z = MFMA16(kfa[0], qf[ntq][0], z);
        z = MFMA16(kfa[1], qf[ntq][1], z);
        __builtin_amdgcn_s_setprio(0);
        union { __bf16 hh[4]; uint2 u; } pk;
        float p0 = fast_exp2(z[0]);
        float p1 = fast_exp2(z[1]);
        float p2 = fast_exp2(z[2]);
        float p3 = fast_exp2(z[3]);
        pk.hh[0] = (__bf16)p0; pk.hh[1] = (__bf16)p1;
        pk.hh[2] = (__bf16)p2; pk.hh[3] = (__bf16)p3;
        lsum[ntq] += (p0 + p1) + (p2 + p3);
        *(uint2*)&QP[pwoff[ntq][mtk]] = pk.u;
      }
    }

    // V(kv) landed (only its 2 loads outstanding); everyone done reading Ks(kv)
    asm volatile("s_waitcnt vmcnt(0)" ::: "memory");
    __builtin_amdgcn_s_barrier();

    // stage K(kv+KT) -> Ks; overlaps PV below (which reads only Vt + QP)
    if (kv + KT < SKV) {
#pragma unroll
      for (int i = 0; i < 2; ++i) {
        int s = i * 256 + tid, r = s >> 3, slot = s & 7, c = slot ^ (r & 7);
        gld16(&kb[(size_t)(kv + KT + r) * SS + c * 8], &Ks[(i * 256 + (tid & 192)) * 8]);
      }
    }

    // O += P·V  (P rows wave-private; per-wave LDS ops in-order)
#pragma unroll
    for (int kc = 0; kc < 2; ++kc) {
      s16x8 pf[2], vf[4];
#pragma unroll
      for (int mt2 = 0; mt2 < 2; ++mt2)
        pf[mt2] = *(const s16x8*)&QP[proff[mt2][kc]];
#pragma unroll
      for (int ntd = 0; ntd < 4; ++ntd)
        vf[ntd] = *(const s16x8*)&Vt[voff[kc][ntd]];
      __builtin_amdgcn_s_setprio(1);
#pragma unroll
      for (int mt2 = 0; mt2 < 2; ++mt2)
#pragma unroll
        for (int ntd = 0; ntd < 4; ++ntd)
          oacc[mt2][ntd] = MFMA16(pf[mt2], vf[ntd], oacc[mt2][ntd]);
      __builtin_amdgcn_s_setprio(0);
    }
  }

#pragma unroll
  for (int nt = 0; nt < 2; ++nt) {
    lsum[nt] += __shfl_xor(lsum[nt], 16);
    lsum[nt] += __shfl_xor(lsum[nt], 32);
  }
#pragma unroll
  for (int mt2 = 0; mt2 < 2; ++mt2)
#pragma unroll
    for (int r = 0; r < 4; ++r) {
      float l = __shfl(lsum[mt2], quad * 4 + r);
      float linv = 1.0f / l;
      int row = q0 + wid * 32 + mt2 * 16 + quad * 4 + r;
#pragma unroll
      for (int ntd = 0; ntd < 4; ++ntd)
        ob[(size_t)row * SS + ntd * 16 + l16] = (__bf16)(oacc[mt2][ntd][r] * linv);
    }
}

// ---------------- round-3 flash attention (fallback path, scalar V scatter) ----------------
__global__ void __launch_bounds__(256)
attn_kernel(const __bf16* __restrict__ qg, const __bf16* __restrict__ kg,
            const __bf16* __restrict__ vg, __bf16* __restrict__ og) {
  constexpr int D = 64, SKV = 2048, QT = 128, KT = 64, SS = 1024;
  constexpr int LDP = 72, LDV = 72;
  __shared__ __attribute__((aligned(16))) __bf16 QP[QT * LDP];
  __shared__ __attribute__((aligned(16))) __bf16 Ks[KT * D];
  __shared__ __attribute__((aligned(16))) __bf16 Vts[D * LDV];

  const int tid = threadIdx.x;
  const int wid = tid >> 6, lane = tid & 63;
  const int quad = lane >> 4, l16 = lane & 15;
  const int b = blockIdx.y >> 4, h = blockIdx.y & 15;
  const int q0 = blockIdx.x * QT;

  const __bf16* qb = qg + (size_t)b * 2048 * SS + h * D;
  const __bf16* kb = kg + (size_t)b * 2048 * SS + h * D;
  const __bf16* vb = vg + (size_t)b * 2048 * SS + h * D;
  __bf16* ob = og + (size_t)b * 2048 * SS + h * D;

#pragma unroll
  for (int i = 0; i < 4; ++i) {
    int s = i * 256 + tid, r = s >> 3, slot = s & 7, c = slot ^ (r & 7);
    gld16(&qb[(size_t)(q0 + r) * SS + c * 8], &QP[(i * 256 + (tid & 192)) * 8]);
  }
  __syncthreads();

  s16x8 qf[2][2];
#pragma unroll
  for (int nt = 0; nt < 2; ++nt)
#pragma unroll
    for (int kc = 0; kc < 2; ++kc) {
      int row = wid * 32 + nt * 16 + l16;
      qf[nt][kc] = *(const s16x8*)&QP[row * 64 + (((quad + kc * 4) ^ (row & 7)) * 8)];
    }
  __syncthreads();

  float lsum[2] = {0.f, 0.f};
  f32x4 oacc[2][4];
#pragma unroll
  for (int mt = 0; mt < 2; ++mt)
#pragma unroll
    for (int nt = 0; nt < 4; ++nt) oacc[mt][nt] = (f32x4){0.f, 0.f, 0.f, 0.f};

  for (int kv = 0; kv < SKV; kv += KT) {
#pragma unroll
    for (int i = 0; i < 2; ++i) {
      int s = i * 256 + tid, r = s >> 3, slot = s & 7, c = slot ^ (r & 7);
      gld16(&kb[(size_t)(kv + r) * SS + c * 8], &Ks[(i * 256 + (tid & 192)) * 8]);
    }
#pragma unroll
    for (int i = 0; i < 2; ++i) {
      int s = i * 256 + tid, r = s >> 3, mc = s & 7;
      uint4 t = *(const uint4*)&vb[(size_t)(kv + r) * SS + mc * 8];
      const __bf16* tp = (const __bf16*)&t;
      int colbase = r ^ (mc << 3);
#pragma unroll
      for (int jj = 0; jj < 8; ++jj) Vts[(mc * 8 + jj) * LDV + colbase] = tp[jj];
    }
    __syncthreads();

#pragma unroll
    for (int mtk = 0; mtk < 4; ++mtk) {
      s16x8 kfa[2];
#pragma unroll
      for (int kc = 0; kc < 2; ++kc) {
        int row = mtk * 16 + l16;
        kfa[kc] = *(const s16x8*)&Ks[row * 64 + (((quad + kc * 4) ^ (row & 7)) * 8)];
      }
#pragma unroll
      for (int ntq = 0; ntq < 2; ++ntq) {
        f32x4 z = (f32x4){0.f, 0.f, 0.f, 0.f};
        z = MFMA16(kfa[0], qf[ntq][0], z);
        z = MFMA16(kfa[1], qf[ntq][1], z);
        union { __bf16 hh[4]; uint2 u; } pk;
        float ps = 0.f;
#pragma unroll
        for (int r = 0; r < 4; ++r) {
          float p = __builtin_exp2f(fminf(z[r], 80.f));
          ps += p;
          pk.hh[r] = (__bf16)p;
        }
        lsum[ntq] += ps;
        int row = wid * 32 + ntq * 16 + l16;
        *(uint2*)&QP[row * LDP + mtk * 16 + quad * 4] = pk.u;
      }
    }

#pragma unroll
    for (int kc = 0; kc < 2; ++kc) {
      s16x8 pf[2], vf[4];
#pragma unroll
      for (int mt2 = 0; mt2 < 2; ++mt2)
        pf[mt2] = *(const s16x8*)&QP[(wid * 32 + mt2 * 16 + l16) * LDP + kc * 32 + quad * 8];
#pragma unroll
      for (int ntd = 0; ntd < 4; ++ntd) {
        int d = ntd * 16 + l16;
        int col0 = (kc * 32 + quad * 8) ^ ((((d >> 3) & 7)) << 3);
        vf[ntd] = *(const s16x8*)&Vts[d * LDV + col0];
      }
#pragma unroll
      for (int mt2 = 0; mt2 < 2; ++mt2)
#pragma unroll
        for (int ntd = 0; ntd < 4; ++ntd)
          oacc[mt2][ntd] = MFMA16(pf[mt2], vf[ntd], oacc[mt2][ntd]);
    }
    __syncthreads();
  }

#pragma unroll
  for (int nt = 0; nt < 2; ++nt) {
    lsum[nt] += __shfl_xor(lsum[nt], 16);
    lsum[nt] += __shfl_xor(lsum[nt], 32);
  }
#pragma unroll
  for (int mt2 = 0; mt2 < 2; ++mt2)
#pragma unroll
    for (int r = 0; r < 4; ++r) {
      float l = __shfl(lsum[mt2], quad * 4 + r);
      float linv = 1.0f / l;
      int row = q0 + wid * 32 + mt2 * 16 + quad * 4 + r;
#pragma unroll
      for (int ntd = 0; ntd < 4; ++ntd)
        ob[(size_t)row * SS + ntd * 16 + l16] = (__bf16)(oacc[mt2][ntd][r] * linv);
    }
}

// ---------------- launch ----------------
extern "C" void kernel_launch(void* const* d_in, const int* in_sizes, int n_in,
                              void* d_out, int out_size, void* d_ws, size_t ws_size,
                              hipStream_t stream) {
  const void* x  = d_in[0];  // [4,2048,1024]
  const void* y  = d_in[1];
  const void* Wv = d_in[2];  // [1024,1024] (in,out)
  const void* Wk = d_in[3];
  const void* Wq = d_in[4];
  const void* Wu = d_in[5];  // [1024,64]
  const void* bu = d_in[6];  // [64]

  const float sc  = 0.17677669529663687f;                        // 1024^-0.25
  const float scq = 0.17677669529663687f * 1.4426950408889634f;  // + log2(e) fold

  constexpr size_t NTOK = (size_t)8192 * 1024;
  constexpr size_t TB = NTOK * 2;

  char* p = (char*)d_ws;
  int* flag = (int*)p; p += 256;
  __bf16* qb = (__bf16*)p; p += TB;
  __bf16* kb = (__bf16*)p; p += TB;
  __bf16* vb = (__bf16*)p; p += TB;   // fast path: used as vbT
  __bf16* WuT = (__bf16*)p; p += (size_t)64 * 1024 * 2;

  const size_t fast_need = 256 + 3 * TB + (size_t)64 * 1024 * 2 + 2 * TB + 3 * (size_t)1024 * 1024 * 2;
  if (ws_size >= fast_need) {
    __bf16* xb = (__bf16*)p; p += TB;
    __bf16* yb = (__bf16*)p; p += TB;
    __bf16* WqkvT = (__bf16*)p;  // 3 x [1024][1024]
    __bf16* vbT = vb;
    __bf16* ob  = xb;  // xb dead after gemm_qkv

    pre_kernel<<<dim3(5184), 256, 0, stream>>>(x, y, Wq, Wk, Wv, Wu, xb, yb, WqkvT, WuT);

    gemm_qkv<<<dim3(1536), 256, 0, stream>>>(xb, yb, WqkvT, qb, kb, vbT, scq, sc);

    attn5_kernel<<<dim3(1024), 256, 0, stream>>>(qb, kb, vbT, ob);

    gemm_out<<<dim3(256), 256, 0, stream>>>(ob, WuT, d_out, bu, (const unsigned short*)x);
  } else {
    __bf16* region = (__bf16*)p;
    __bf16* WqT = region;
    __bf16* WkT = region + (size_t)1024 * 1024;
    __bf16* WvT = region + (size_t)2 * 1024 * 1024;
    __bf16* ob  = region;

    probe_kernel<<<1, 64, 0, stream>>>((const unsigned short*)x, flag);
    tr3_kernel<<<dim3(32, 32, 4), 256, 0, stream>>>(Wq, Wk, Wv, Wu, WqT, WuT, flag);

    gemm_bt<128, 128, false, false, true><<<dim3(64, 8), 256, 0, stream>>>(
        y, WqT, qb, nullptr, 8192, 1024, 1024, scq, flag);
    gemm_bt<128, 128, false, false, true><<<dim3(64, 8), 256, 0, stream>>>(
        x, WkT, kb, nullptr, 8192, 1024, 1024, sc, flag);
    gemm_bt<128, 128, false, false, true><<<dim3(64, 8), 256, 0, stream>>>(
        x, WvT, vb, nullptr, 8192, 1024, 1024, 1.0f, flag);

    attn_kernel<<<dim3(16, 64), 256, 0, stream>>>(qb, kb, vb, ob);

    gemm_bt<128, 64, true, true, false><<<dim3(64, 1), 256, 0, stream>>>(
        ob, WuT, d_out, bu, 8192, 64, 1024, 1.0f, flag);
  }
}